// Round 7
// baseline (1774.202 us; speedup 1.0000x reference)
//
#include <hip/hip_runtime.h>
#include <hip/hip_bf16.h>
#include <hip/hip_cooperative_groups.h>
#include <cstdint>

namespace cg = cooperative_groups;

// Problem constants
#define BB 16
#define NN 4096
#define MM 1024
#define KNB 16
#define CIN 64
#define COUT 128
#define RTOT (BB*MM*KNB)   // 262144 rows
#define AP1 104            // gemm1 LDS row stride (96 used + 8 pad), bf16
#define AP2 136            // gemm2 LDS row stride (128 + 8 pad), bf16

typedef __attribute__((ext_vector_type(8))) short short8v;
typedef __attribute__((ext_vector_type(4))) float floatx4;

// ---------- helpers ----------
__device__ __forceinline__ float bflo(uint32_t u){ return __uint_as_float(u << 16); }
__device__ __forceinline__ float bfhi(uint32_t u){ return __uint_as_float(u & 0xffff0000u); }
__device__ __forceinline__ uint32_t f2bf_pk(float a, float b){
  uint32_t ua = __float_as_uint(a), ub = __float_as_uint(b);
  ua += 0x7fffu + ((ua >> 16) & 1u);   // RNE
  ub += 0x7fffu + ((ub >> 16) & 1u);
  return (ua >> 16) | (ub & 0xffff0000u);
}
__device__ __forceinline__ uint16_t f2bf1(float a){
  uint32_t u = __float_as_uint(a);
  u += 0x7fffu + ((u >> 16) & 1u);
  return (uint16_t)(u >> 16);
}

// ---------- LDS structs ----------
struct FpsS { float pc[NN*3]; float4 sel[MM]; float2 cand[2][32]; };      // 66048 B
struct TrS  { float t[64][65]; };                                         // 16640 B
struct G1S  { uint16_t Bh[128*AP1]; uint16_t Ah[128*AP1]; uint16_t Dh[128*AP2];
              float ssum[128]; float ssq[128]; };                         // 89088 B
struct G2S  { uint16_t Bh[128*AP2]; uint16_t Ah[128*AP2];
              float scb[128]; float shb[128]; float ssum[128]; float ssq[128]; }; // 71680 B
struct PoolS{ float ot[128*65]; float scs[128]; float shs[128]; };        // 34304 B
union PreU  { FpsS fps; TrS tr; };
union TailU { G1S g1; G2S g2; PoolS pool; };

// ================= K1: pre-work kernel (plain launch; kernel boundary = coherence) ==========
// blocks 0-15: FPS (round-5-verbatim mechanics) ; blocks 16-255: stat-zero + p1n + transpose
__global__ __launch_bounds__(512, 2) void k_pre(
    const float* __restrict__ p1, const float* __restrict__ x1,
    float* __restrict__ outp2, float* __restrict__ p2w,
    float4* __restrict__ p1n, uint16_t* __restrict__ xtb, float* __restrict__ Sz)
{
  __shared__ PreU u;
  const int blk = blockIdx.x, tid = threadIdx.x;
  const int lane = tid & 63, wid = tid >> 6;

  if (blk < 16){
    int b = blk;
    const float* pb = p1 + (size_t)b*NN*3;
    float4 f[6];
    const float4* src = (const float4*)(pb + tid*24);
    #pragma unroll
    for (int j=0;j<6;j++) f[j] = src[j];
    #pragma unroll
    for (int j=0;j<6;j++) *(float4*)(u.fps.pc + tid*24 + j*4) = f[j];
    const float* fa = (const float*)f;
    float px[8],py[8],pz[8],dist[8];
    #pragma unroll
    for (int j=0;j<8;j++){ px[j]=fa[3*j]; py[j]=fa[3*j+1]; pz[j]=fa[3*j+2]; dist[j]=1e10f; }
    __syncthreads();
    float cx = u.fps.pc[0], cy = u.fps.pc[1], cz = u.fps.pc[2];
    if (tid==0) u.fps.sel[0] = make_float4(cx, cy, cz, 0.f);
    int g0 = tid*8;

    #define DPP_STEP(ctrl) { \
      int ov_i = __builtin_amdgcn_update_dpp(__float_as_int(mval), __float_as_int(mval), (ctrl), 0xf, 0xf, false); \
      int oi   = __builtin_amdgcn_update_dpp(midx, midx, (ctrl), 0xf, 0xf, false); \
      float ov = __int_as_float(ov_i); \
      if (ov > mval || (ov == mval && oi < midx)){ mval = ov; midx = oi; } }

    for (int i=1;i<MM;i++){
      float nd[8];
      #pragma unroll
      for (int j=0;j<8;j++){
        float dx=__fsub_rn(px[j],cx), dy=__fsub_rn(py[j],cy), dz=__fsub_rn(pz[j],cz);
        float d = __fadd_rn(__fadd_rn(__fmul_rn(dx,dx),__fmul_rn(dy,dy)),__fmul_rn(dz,dz));
        nd[j] = fminf(dist[j], d); dist[j] = nd[j];
      }
      float tv[4]; int ti[4];
      #pragma unroll
      for (int j=0;j<4;j++){
        bool r = nd[2*j+1] > nd[2*j];
        tv[j] = r ? nd[2*j+1] : nd[2*j];
        ti[j] = g0 + 2*j + (r ? 1 : 0);
      }
      { bool r = tv[1] > tv[0]; tv[0] = r?tv[1]:tv[0]; ti[0] = r?ti[1]:ti[0]; }
      { bool r = tv[3] > tv[2]; tv[2] = r?tv[3]:tv[2]; ti[2] = r?ti[3]:ti[2]; }
      bool rr = tv[2] > tv[0];
      float mval = rr ? tv[2] : tv[0];
      int   midx = rr ? ti[2] : ti[0];
      DPP_STEP(0xB1); DPP_STEP(0x4E); DPP_STEP(0x124); DPP_STEP(0x128);
      int pbuf = i & 1;
      if ((lane & 15) == 0) u.fps.cand[pbuf][wid*4 + (lane>>4)] = make_float2(mval, __int_as_float(midx));
      __syncthreads();
      float2 c0 = u.fps.cand[pbuf][lane & 15];
      float2 c1 = u.fps.cand[pbuf][16 + (lane & 15)];
      mval = c0.x; midx = __float_as_int(c0.y);
      { if (c1.x > mval){ mval = c1.x; midx = __float_as_int(c1.y); } }
      DPP_STEP(0xB1); DPP_STEP(0x4E); DPP_STEP(0x124); DPP_STEP(0x128);
      cx = u.fps.pc[midx*3+0]; cy = u.fps.pc[midx*3+1]; cz = u.fps.pc[midx*3+2];
      if (tid==0) u.fps.sel[i] = make_float4(cx, cy, cz, 0.f);
    }
    #undef DPP_STEP
    __syncthreads();
    for (int e = tid; e < MM; e += 512){
      float4 s = u.fps.sel[e];
      float n2 = __fadd_rn(__fadd_rn(__fmul_rn(s.x,s.x),__fmul_rn(s.y,s.y)),__fmul_rn(s.z,s.z));
      float* o = outp2 + ((size_t)b*MM + e)*3;
      o[0]=s.x; o[1]=s.y; o[2]=s.z;
      *(float4*)(p2w + ((size_t)b*MM + e)*4) = make_float4(s.x, s.y, s.z, n2);
    }
  } else {
    // zero stat copies (S1+S2 contiguous, 16384 floats)
    for (int i = (blk-16)*512 + tid; i < 16384; i += 240*512) Sz[i] = 0.f;
    // prep p1n
    for (int i = (blk-16)*512 + tid; i < BB*NN; i += 240*512){
      float x = p1[(size_t)i*3+0], y = p1[(size_t)i*3+1], z = p1[(size_t)i*3+2];
      float n = __fadd_rn(__fadd_rn(__fmul_rn(x,x),__fmul_rn(y,y)),__fmul_rn(z,z));
      p1n[i] = make_float4(x,y,z,n);
    }
    // transpose x1 -> xtb (bf16), 64x64 tiles
    for (int tile = blk-16; tile < 1024; tile += 240){
      int b = tile >> 6, n0 = (tile & 63)*64;
      __syncthreads();
      int c = tid >> 3, q = tid & 7;
      const float* src = x1 + ((size_t)(b*64 + c))*NN + n0 + q*8;
      float4 f0 = *(const float4*)src, f1 = *(const float4*)(src+4);
      u.tr.t[c][q*8+0]=f0.x; u.tr.t[c][q*8+1]=f0.y; u.tr.t[c][q*8+2]=f0.z; u.tr.t[c][q*8+3]=f0.w;
      u.tr.t[c][q*8+4]=f1.x; u.tr.t[c][q*8+5]=f1.y; u.tr.t[c][q*8+6]=f1.z; u.tr.t[c][q*8+7]=f1.w;
      __syncthreads();
      int n = tid >> 3;
      uint32_t* dst = (uint32_t*)(xtb + ((size_t)(b*NN + n0 + n))*64 + q*8);
      #pragma unroll
      for (int j=0;j<4;j++)
        dst[j] = f2bf_pk(u.tr.t[q*8+2*j][n], u.tr.t[q*8+2*j+1][n]);
    }
  }
}

// ================= K2: cooperative tail: knn -> gemm1 -> gemm2+pool-extrema -> pool ==========
__global__ __launch_bounds__(512, 2) void k_tail(
    const float* __restrict__ p1,
    const float* __restrict__ w1, const float* __restrict__ g1v, const float* __restrict__ b1v,
    const float* __restrict__ w2, const float* __restrict__ g2v, const float* __restrict__ b2v,
    const float4* __restrict__ p1n, const float* __restrict__ p2w, const uint16_t* __restrict__ xtb,
    int* __restrict__ iknn, float* __restrict__ S1, float* __restrict__ S2,
    uint16_t* __restrict__ h1, float* __restrict__ hmax, float* __restrict__ hmin,
    float* __restrict__ out1)
{
  __shared__ TailU u;
  cg::grid_group grid = cg::this_grid();
  const int blk = blockIdx.x, tid = threadIdx.x;
  const int lane = tid & 63, wid = tid >> 6;

  // ---------------- phase 1: kNN (8 queries per wave, grid-stride) ----------------
  {
    int gw = blk*8 + wid;
    for (int q = gw; q < BB*MM; q += 2048){
      int b = q >> 10;
      const float4 qv = *(const float4*)(p2w + (size_t)q*4);
      const float4* pbn = p1n + (size_t)b*NN;
      float bd[16]; int bi[16];
      #pragma unroll
      for (int s=0;s<16;s++){ bd[s] = 1e30f; bi[s] = 0; }
      float wv = 1e30f; int wslot = 0;

      #define KPROC(T, PV) { \
        float dot = fmaf(qv.z, (PV).z, fmaf(qv.y, (PV).y, __fmul_rn(qv.x, (PV).x))); \
        float d2 = __fsub_rn(__fadd_rn(qv.w, (PV).w), __fmul_rn(2.0f, dot)); \
        if (d2 < wv){ \
          int c = (T)*64 + lane; \
          _Pragma("unroll") \
          for (int s=0;s<16;s++) if (s==wslot){ bd[s]=d2; bi[s]=c; } \
          wv = bd[0]; wslot = 0; \
          _Pragma("unroll") \
          for (int s=1;s<16;s++) if (bd[s] > wv){ wv = bd[s]; wslot = s; } \
        } }

      float4 cur = pbn[lane];
      for (int t=0;t<63;t++){
        float4 nx = pbn[(t+1)*64 + lane];
        KPROC(t, cur);
        cur = nx;
      }
      KPROC(63, cur);
      #undef KPROC

      float lv = bd[0]; int ls = 0;
      #pragma unroll
      for (int s=1;s<16;s++) if (bd[s] < lv){ lv = bd[s]; ls = s; }
      for (int r=0;r<16;r++){
        float rv = lv; int rl = lane;
        #pragma unroll
        for (int off=32; off>=1; off>>=1){
          float ov = __shfl_xor(rv, off); int ol = __shfl_xor(rl, off);
          if (ov < rv || (ov == rv && ol < rl)){ rv = ov; rl = ol; }
        }
        if (lane == rl){
          int idx = 0;
          #pragma unroll
          for (int s=0;s<16;s++) if (s==ls) idx = bi[s];
          iknn[(size_t)q*16 + r] = idx;
          #pragma unroll
          for (int s=0;s<16;s++) if (s==ls) bd[s] = 1e30f;
          lv = bd[0]; ls = 0;
          #pragma unroll
          for (int s=1;s<16;s++) if (bd[s] < lv){ lv = bd[s]; ls = s; }
        }
      }
    }
  }
  __threadfence();
  grid.sync();
  __threadfence();

  // ---------------- phase 2: GEMM1 (bf16 MFMA, fused gather), 128-row tiles ----------------
  {
    for (int e = tid; e < 128*96; e += 512){
      int o = e / 96, k = e - o*96;
      float v = (k < 64) ? w1[o*67 + 3 + k] : ((k < 67) ? w1[o*67 + (k-64)] : 0.f);
      u.g1.Bh[o*AP1 + k] = f2bf1(v);
    }
    if (tid < 128){ u.g1.ssum[tid]=0.f; u.g1.ssq[tid]=0.f; }
    int ml = lane & 15, quad = lane >> 4, m0 = wid*16;
    for (int tile = blk; tile < 2048; tile += 256){
      int r0 = tile * 128;
      int b = r0 >> 14;
      // stage A: cols 0..63 by threads 0..255; cols 64..95 (rel + zero pad) by 256..511
      if (tid < 256){
        int row = tid >> 1, hf = tid & 1;
        int n = iknn[r0 + row];
        const uint4* s4 = (const uint4*)(xtb + ((size_t)(b*NN + n))*64 + hf*32);
        uint4* d4 = (uint4*)(u.g1.Ah + row*AP1 + hf*32);
        #pragma unroll
        for (int j=0;j<4;j++) d4[j] = s4[j];
      } else {
        int t2 = tid - 256;
        int row = t2 >> 1, part = t2 & 1;
        uint4* d4 = (uint4*)(u.g1.Ah + row*AP1 + 64 + part*16);
        if (part == 0){
          int r = r0 + row;
          int n = iknn[r];
          int mg = r >> 4;
          const float* pp = p1 + ((size_t)(b*NN + n))*3;
          const float* qq = p2w + (size_t)mg*4;
          float rx = __fsub_rn(pp[0], qq[0]);
          float ry = __fsub_rn(pp[1], qq[1]);
          float rz = __fsub_rn(pp[2], qq[2]);
          d4[0] = make_uint4(f2bf_pk(rx, ry), f2bf_pk(rz, 0.f), 0u, 0u);
          d4[1] = make_uint4(0u,0u,0u,0u);
        } else {
          d4[0] = make_uint4(0u,0u,0u,0u);
          d4[1] = make_uint4(0u,0u,0u,0u);
        }
      }
      __syncthreads();
      short8v af[3];
      #pragma unroll
      for (int kc=0;kc<3;kc++)
        af[kc] = *(const short8v*)(u.g1.Ah + (m0+ml)*AP1 + kc*32 + quad*8);
      floatx4 acc[8];
      #pragma unroll
      for (int ct=0;ct<8;ct++) acc[ct] = (floatx4){0.f,0.f,0.f,0.f};
      #pragma unroll
      for (int ct=0;ct<8;ct++){
        #pragma unroll
        for (int kc=0;kc<3;kc++){
          short8v bf = *(const short8v*)(u.g1.Bh + (ct*16+ml)*AP1 + kc*32 + quad*8);
          acc[ct] = __builtin_amdgcn_mfma_f32_16x16x32_bf16(af[kc], bf, acc[ct], 0, 0, 0);
        }
      }
      float csum[8], csq[8];
      #pragma unroll
      for (int ct=0;ct<8;ct++){
        float a0=acc[ct][0], a1=acc[ct][1], a2=acc[ct][2], a3=acc[ct][3];
        float s = (a0+a1)+(a2+a3);
        float qq2 = (a0*a0+a1*a1)+(a2*a2+a3*a3);
        s += __shfl_xor(s,16);  s += __shfl_xor(s,32);
        qq2 += __shfl_xor(qq2,16); qq2 += __shfl_xor(qq2,32);
        csum[ct]=s; csq[ct]=qq2;
        #pragma unroll
        for (int r=0;r<4;r++)
          u.g1.Dh[(m0 + quad*4 + r)*AP2 + ct*16 + ml] = f2bf1(acc[ct][r]);
      }
      #pragma unroll
      for (int j=0;j<2;j++){
        int ct = quad*2 + j, col = ct*16 + ml;
        atomicAdd(&u.g1.ssum[col], csum[ct]);
        atomicAdd(&u.g1.ssq[col],  csq[ct]);
      }
      __syncthreads();
      {
        int row = tid >> 2, seg = tid & 3;
        uint4* dst = (uint4*)(h1 + ((size_t)(r0+row))*128 + seg*32);
        const uint4* s4 = (const uint4*)(u.g1.Dh + row*AP2 + seg*32);
        #pragma unroll
        for (int q2=0;q2<4;q2++) dst[q2] = s4[q2];
      }
    }
    int cp = (blk & 31)*256;
    if (tid < 128){ atomicAdd(&S1[cp+tid], u.g1.ssum[tid]); atomicAdd(&S1[cp+128+tid], u.g1.ssq[tid]); }
  }
  __threadfence();
  grid.sync();
  __threadfence();

  // ---------------- phase 3: GEMM2 (bf16 MFMA) + fused k-pool extrema ----------------
  {
    if (tid < 128){
      float s=0.f, q=0.f;
      for (int c=0;c<32;c++){ s += S1[c*256+tid]; q += S1[c*256+128+tid]; }
      float inv = 1.0f / (float)RTOT;
      float mean = s * inv;
      float var  = q * inv - mean*mean;
      float rs = 1.0f / sqrtf(var + 1e-5f);
      float scv = g1v[tid] * rs;
      u.g2.scb[tid] = scv;
      u.g2.shb[tid] = b1v[tid] - mean*scv;
      u.g2.ssum[tid] = 0.f; u.g2.ssq[tid] = 0.f;
    }
    {
      int o = tid >> 2, q4 = tid & 3;
      const float4* wr = (const float4*)(w2 + (size_t)o*128 + q4*32);
      uint32_t* bd = (uint32_t*)(u.g2.Bh + o*AP2 + q4*32);
      #pragma unroll
      for (int j=0;j<8;j++){
        float4 v = wr[j];
        bd[2*j]   = f2bf_pk(v.x, v.y);
        bd[2*j+1] = f2bf_pk(v.z, v.w);
      }
    }
    __syncthreads();
    int ml = lane & 15, quad = lane >> 4, m0 = wid*16;
    for (int tile = blk; tile < 2048; tile += 256){
      int r0 = tile * 128;
      {
        int row = tid >> 2, seg = tid & 3;
        const uint4* hp4 = (const uint4*)(h1 + ((size_t)(r0+row))*128 + seg*32);
        #pragma unroll
        for (int q=0;q<4;q++){
          uint4 uu = hp4[q];
          int cg = seg*32 + q*8;
          uint32_t wv4[4] = {uu.x,uu.y,uu.z,uu.w};
          uint32_t ov[4];
          #pragma unroll
          for (int t=0;t<4;t++){
            int c = cg + t*2;
            float a0 = fmaxf(fmaf(bflo(wv4[t]), u.g2.scb[c],   u.g2.shb[c]),   0.f);
            float a1 = fmaxf(fmaf(bfhi(wv4[t]), u.g2.scb[c+1], u.g2.shb[c+1]), 0.f);
            ov[t] = f2bf_pk(a0, a1);
          }
          *(uint4*)(u.g2.Ah + row*AP2 + cg) = make_uint4(ov[0],ov[1],ov[2],ov[3]);
        }
      }
      __syncthreads();
      short8v af[4];
      #pragma unroll
      for (int kc=0;kc<4;kc++)
        af[kc] = *(const short8v*)(u.g2.Ah + (m0+ml)*AP2 + kc*32 + quad*8);
      floatx4 acc[8];
      #pragma unroll
      for (int ct=0;ct<8;ct++) acc[ct] = (floatx4){0.f,0.f,0.f,0.f};
      #pragma unroll
      for (int ct=0;ct<8;ct++){
        #pragma unroll
        for (int kc=0;kc<4;kc++){
          short8v bf = *(const short8v*)(u.g2.Bh + (ct*16+ml)*AP2 + kc*32 + quad*8);
          acc[ct] = __builtin_amdgcn_mfma_f32_16x16x32_bf16(af[kc], bf, acc[ct], 0, 0, 0);
        }
      }
      int mrow = tile*8 + wid;
      float cm[8], cn[8], cs[8], cq[8];
      #pragma unroll
      for (int ct=0;ct<8;ct++){
        float a0=acc[ct][0], a1=acc[ct][1], a2=acc[ct][2], a3=acc[ct][3];
        float mx = fmaxf(fmaxf(a0,a1), fmaxf(a2,a3));
        float mn = fminf(fminf(a0,a1), fminf(a2,a3));
        float s  = (a0+a1)+(a2+a3);
        float q2 = (a0*a0+a1*a1)+(a2*a2+a3*a3);
        mx = fmaxf(mx, __shfl_xor(mx,16)); mx = fmaxf(mx, __shfl_xor(mx,32));
        mn = fminf(mn, __shfl_xor(mn,16)); mn = fminf(mn, __shfl_xor(mn,32));
        s += __shfl_xor(s,16);  s += __shfl_xor(s,32);
        q2 += __shfl_xor(q2,16); q2 += __shfl_xor(q2,32);
        cm[ct]=mx; cn[ct]=mn; cs[ct]=s; cq[ct]=q2;
      }
      #pragma unroll
      for (int j=0;j<2;j++){
        int ct = quad*2 + j, col = ct*16 + ml;
        hmax[(size_t)mrow*128 + col] = cm[ct];
        hmin[(size_t)mrow*128 + col] = cn[ct];
        atomicAdd(&u.g2.ssum[col], cs[ct]);
        atomicAdd(&u.g2.ssq[col],  cq[ct]);
      }
      __syncthreads();
    }
    int cp = (blk & 31)*256;
    if (tid < 128){ atomicAdd(&S2[cp+tid], u.g2.ssum[tid]); atomicAdd(&S2[cp+128+tid], u.g2.ssq[tid]); }
  }
  __threadfence();
  grid.sync();
  __threadfence();

  // ---------------- phase 4: bn2+relu on pooled extrema, transposed write ----------------
  {
    if (tid < 128){
      float s=0.f, q=0.f;
      for (int c=0;c<32;c++){ s += S2[c*256+tid]; q += S2[c*256+128+tid]; }
      float inv = 1.0f / (float)RTOT;
      float mean = s * inv;
      float var  = q * inv - mean*mean;
      float rs = 1.0f / sqrtf(var + 1e-5f);
      float scv = g2v[tid] * rs;
      u.pool.scs[tid] = scv;
      u.pool.shs[tid] = b2v[tid] - mean*scv;
    }
    __syncthreads();
    int b = blk >> 4, m0 = (blk & 15)*64;
    int ml2 = tid >> 3, c0 = (tid & 7)*16;
    int gm = b*MM + m0 + ml2;
    #pragma unroll
    for (int j4=0;j4<4;j4++){
      float4 hx = *(const float4*)(hmax + (size_t)gm*128 + c0 + j4*4);
      float4 hn = *(const float4*)(hmin + (size_t)gm*128 + c0 + j4*4);
      float hv[4] = {hx.x, hx.y, hx.z, hx.w};
      float nv[4] = {hn.x, hn.y, hn.z, hn.w};
      #pragma unroll
      for (int e=0;e<4;e++){
        int c = c0 + j4*4 + e;
        float sc = u.pool.scs[c], sh = u.pool.shs[c];
        float h = (sc >= 0.f) ? hv[e] : nv[e];
        u.pool.ot[c*65 + ml2] = fmaxf(fmaf(h, sc, sh), 0.f);
      }
    }
    __syncthreads();
    int o = tid >> 2, mh = (tid & 3)*16;
    float* dst = out1 + ((size_t)(b*COUT + o))*MM + m0 + mh;
    #pragma unroll
    for (int j=0;j<4;j++){
      float4 v;
      v.x=u.pool.ot[o*65+mh+j*4+0]; v.y=u.pool.ot[o*65+mh+j*4+1];
      v.z=u.pool.ot[o*65+mh+j*4+2]; v.w=u.pool.ot[o*65+mh+j*4+3];
      *(float4*)(dst + j*4) = v;
    }
  }
}

extern "C" void kernel_launch(void* const* d_in, const int* in_sizes, int n_in,
                              void* d_out, int out_size, void* d_ws, size_t ws_size,
                              hipStream_t stream) {
  (void)in_sizes; (void)n_in; (void)out_size; (void)ws_size;
  const float* p1 = (const float*)d_in[0];
  const float* x1 = (const float*)d_in[1];
  const float* w1 = (const float*)d_in[2];
  const float* g1 = (const float*)d_in[3];
  const float* b1 = (const float*)d_in[4];
  const float* w2 = (const float*)d_in[5];
  const float* g2 = (const float*)d_in[6];
  const float* b2 = (const float*)d_in[7];
  float* out = (float*)d_out;
  float* ws  = (float*)d_ws;

  // ws map (float indices)
  uint16_t* xtb = (uint16_t*)ws;                    // [B,N,64] bf16
  float4* p1n   = (float4*)(ws + 2097152);          // [B,N]
  int*    iknn  = (int*)(ws + 2359296);             // [B,M,16]
  float*  p2w   = ws + 2621440;                     // [B,M,4]
  float*  S1    = ws + 2686976;                     // 8192
  float*  S2    = ws + 2695168;                     // 8192
  uint16_t* h1  = (uint16_t*)(ws + 2703872);        // [R,128] bf16
  float*  hmax  = ws + 19481088;                    // [B*M,128]
  float*  hmin  = ws + 21578240;                    // [B*M,128]
  float*  outp2 = out;                              // [B,M,3]
  float*  out1  = out + 49152;                      // [B,128,M]

  k_pre<<<256, 512, 0, stream>>>(p1, x1, outp2, p2w, p1n, xtb, S1);

  void* args[] = { (void*)&p1, (void*)&w1, (void*)&g1, (void*)&b1,
                   (void*)&w2, (void*)&g2, (void*)&b2,
                   (void*)&p1n, (void*)&p2w, (void*)&xtb,
                   (void*)&iknn, (void*)&S1, (void*)&S2,
                   (void*)&h1, (void*)&hmax, (void*)&hmin, (void*)&out1 };
  hipLaunchCooperativeKernel((void*)k_tail, dim3(256), dim3(512), args, 0, stream);
}

// Round 8
// 1359.945 us; speedup vs baseline: 1.3046x; 1.3046x over previous
//
#include <hip/hip_runtime.h>
#include <hip/hip_bf16.h>
#include <hip/hip_cooperative_groups.h>
#include <cstdint>

namespace cg = cooperative_groups;

// Problem constants
#define BB 16
#define NN 4096
#define MM 1024
#define KNB 16
#define CIN 64
#define COUT 128
#define RTOT (BB*MM*KNB)   // 262144 rows
#define AP1 104            // gemm1 LDS row stride (96 used + 8 pad), bf16
#define AP2 136            // gemm2 LDS row stride (128 + 8 pad), bf16

typedef __attribute__((ext_vector_type(8))) short short8v;
typedef __attribute__((ext_vector_type(4))) float floatx4;

// ---------- helpers ----------
__device__ __forceinline__ float bflo(uint32_t u){ return __uint_as_float(u << 16); }
__device__ __forceinline__ float bfhi(uint32_t u){ return __uint_as_float(u & 0xffff0000u); }
__device__ __forceinline__ uint32_t f2bf_pk(float a, float b){
  uint32_t ua = __float_as_uint(a), ub = __float_as_uint(b);
  ua += 0x7fffu + ((ua >> 16) & 1u);   // RNE
  ub += 0x7fffu + ((ub >> 16) & 1u);
  return (ua >> 16) | (ub & 0xffff0000u);
}
__device__ __forceinline__ uint16_t f2bf1(float a){
  uint32_t u = __float_as_uint(a);
  u += 0x7fffu + ((u >> 16) & 1u);
  return (uint16_t)(u >> 16);
}

// ---------- LDS ----------
struct FpsS { float pc[NN*3]; float4 sel[MM]; float2 cand[2][32]; };      // 66048 B
struct TrS  { float t[64][65]; };                                         // 16640 B
union PreU  { FpsS fps; TrS tr; };

// ================= K1: FPS (blocks 0-15, incremental p2w publishing) ||
//                       prework then pipelined kNN (blocks 16-255) =================
// Producer-consumer: FPS tid64 logs sel[i] to LDS; every 32 iters flushes 32 p2w
// entries (global) + release-store prog[b]=i+1 (agent scope). kNN waves poll
// prog[b] >= m+1 with acquire before reading p2w[q]. Selection/knn arithmetic
// bit-identical to round 5. Cooperative launch guarantees co-residency (no
// deadlock: producers never wait; consumer spins are bounded).
__global__ __launch_bounds__(512, 2) void k_pre2(
    const float* __restrict__ p1, const float* __restrict__ x1,
    float* __restrict__ outp2, float* __restrict__ p2w,
    float4* __restrict__ p1n, uint16_t* __restrict__ xtb, float* __restrict__ Sz,
    int* __restrict__ iknn, int* __restrict__ prog, int* __restrict__ prep_done)
{
  __shared__ PreU u;
  const int blk = blockIdx.x, tid = threadIdx.x;
  const int lane = tid & 63, wid = tid >> 6;

  if (blk < 16){
    // ---------------- FPS producer ----------------
    int b = blk;
    const float* pb = p1 + (size_t)b*NN*3;
    float4 f[6];
    const float4* src = (const float4*)(pb + tid*24);
    #pragma unroll
    for (int j=0;j<6;j++) f[j] = src[j];
    #pragma unroll
    for (int j=0;j<6;j++) *(float4*)(u.fps.pc + tid*24 + j*4) = f[j];
    const float* fa = (const float*)f;
    float px[8],py[8],pz[8],dist[8];
    #pragma unroll
    for (int j=0;j<8;j++){ px[j]=fa[3*j]; py[j]=fa[3*j+1]; pz[j]=fa[3*j+2]; dist[j]=1e10f; }
    __syncthreads();
    float cx = u.fps.pc[0], cy = u.fps.pc[1], cz = u.fps.pc[2];
    if (tid==64) u.fps.sel[0] = make_float4(cx, cy, cz, 0.f);
    int g0 = tid*8;

    #define DPP_STEP(ctrl) { \
      int ov_i = __builtin_amdgcn_update_dpp(__float_as_int(mval), __float_as_int(mval), (ctrl), 0xf, 0xf, false); \
      int oi   = __builtin_amdgcn_update_dpp(midx, midx, (ctrl), 0xf, 0xf, false); \
      float ov = __int_as_float(ov_i); \
      if (ov > mval || (ov == mval && oi < midx)){ mval = ov; midx = oi; } }

    for (int i=1;i<MM;i++){
      float nd[8];
      #pragma unroll
      for (int j=0;j<8;j++){
        float dx=__fsub_rn(px[j],cx), dy=__fsub_rn(py[j],cy), dz=__fsub_rn(pz[j],cz);
        float d = __fadd_rn(__fadd_rn(__fmul_rn(dx,dx),__fmul_rn(dy,dy)),__fmul_rn(dz,dz));
        nd[j] = fminf(dist[j], d); dist[j] = nd[j];
      }
      float tv[4]; int ti[4];
      #pragma unroll
      for (int j=0;j<4;j++){
        bool r = nd[2*j+1] > nd[2*j];
        tv[j] = r ? nd[2*j+1] : nd[2*j];
        ti[j] = g0 + 2*j + (r ? 1 : 0);
      }
      { bool r = tv[1] > tv[0]; tv[0] = r?tv[1]:tv[0]; ti[0] = r?ti[1]:ti[0]; }
      { bool r = tv[3] > tv[2]; tv[2] = r?tv[3]:tv[2]; ti[2] = r?ti[3]:ti[2]; }
      bool rr = tv[2] > tv[0];
      float mval = rr ? tv[2] : tv[0];
      int   midx = rr ? ti[2] : ti[0];
      DPP_STEP(0xB1); DPP_STEP(0x4E); DPP_STEP(0x124); DPP_STEP(0x128);
      int pbuf = i & 1;
      if ((lane & 15) == 0) u.fps.cand[pbuf][wid*4 + (lane>>4)] = make_float2(mval, __int_as_float(midx));
      __syncthreads();
      float2 c0 = u.fps.cand[pbuf][lane & 15];
      float2 c1 = u.fps.cand[pbuf][16 + (lane & 15)];
      mval = c0.x; midx = __float_as_int(c0.y);
      { if (c1.x > mval){ mval = c1.x; midx = __float_as_int(c1.y); } }
      DPP_STEP(0xB1); DPP_STEP(0x4E); DPP_STEP(0x124); DPP_STEP(0x128);
      cx = u.fps.pc[midx*3+0]; cy = u.fps.pc[midx*3+1]; cz = u.fps.pc[midx*3+2];
      if (tid==64){
        u.fps.sel[i] = make_float4(cx, cy, cz, 0.f);
        if ((i & 31) == 31){
          // flush entries i-31..i to p2w (same thread as sel writes -> in-order), then publish
          for (int e = i-31; e <= i; e++){
            float4 s = u.fps.sel[e];
            float n2 = __fadd_rn(__fadd_rn(__fmul_rn(s.x,s.x),__fmul_rn(s.y,s.y)),__fmul_rn(s.z,s.z));
            *(float4*)(p2w + ((size_t)b*MM + e)*4) = make_float4(s.x, s.y, s.z, n2);
          }
          __hip_atomic_store(&prog[b*16], i+1, __ATOMIC_RELEASE, __HIP_MEMORY_SCOPE_AGENT);
        }
      }
    }
    #undef DPP_STEP
    __syncthreads();
    // outp2 final dump (not consumed in-kernel)
    for (int e = tid; e < MM; e += 512){
      float4 s = u.fps.sel[e];
      float* o = outp2 + ((size_t)b*MM + e)*3;
      o[0]=s.x; o[1]=s.y; o[2]=s.z;
    }
  } else {
    // ---------------- prework ----------------
    for (int i = (blk-16)*512 + tid; i < 16384; i += 240*512) Sz[i] = 0.f;
    for (int i = (blk-16)*512 + tid; i < BB*NN; i += 240*512){
      float x = p1[(size_t)i*3+0], y = p1[(size_t)i*3+1], z = p1[(size_t)i*3+2];
      float n = __fadd_rn(__fadd_rn(__fmul_rn(x,x),__fmul_rn(y,y)),__fmul_rn(z,z));
      p1n[i] = make_float4(x,y,z,n);
    }
    for (int tile = blk-16; tile < 1024; tile += 240){
      int b = tile >> 6, n0 = (tile & 63)*64;
      __syncthreads();
      int c = tid >> 3, q = tid & 7;
      const float* src = x1 + ((size_t)(b*64 + c))*NN + n0 + q*8;
      float4 f0 = *(const float4*)src, f1 = *(const float4*)(src+4);
      u.tr.t[c][q*8+0]=f0.x; u.tr.t[c][q*8+1]=f0.y; u.tr.t[c][q*8+2]=f0.z; u.tr.t[c][q*8+3]=f0.w;
      u.tr.t[c][q*8+4]=f1.x; u.tr.t[c][q*8+5]=f1.y; u.tr.t[c][q*8+6]=f1.z; u.tr.t[c][q*8+7]=f1.w;
      __syncthreads();
      int n = tid >> 3;
      uint32_t* dst = (uint32_t*)(xtb + ((size_t)(b*NN + n0 + n))*64 + q*8);
      #pragma unroll
      for (int j=0;j<4;j++)
        dst[j] = f2bf_pk(u.tr.t[q*8+2*j][n], u.tr.t[q*8+2*j+1][n]);
    }
    // publish prework: every thread fences its own stores, then one count per block
    __threadfence();
    __syncthreads();
    if (tid == 0) atomicAdd(prep_done, 1);
    // wait for all 240 prework blocks (p1n produced by other blocks)
    {
      int pv = 0;
      for (int sp = 0; sp < (1<<20); ++sp){
        if (lane == 0) pv = __hip_atomic_load(prep_done, __ATOMIC_ACQUIRE, __HIP_MEMORY_SCOPE_AGENT);
        pv = __shfl(pv, 0);
        if (pv >= 240) break;
        __builtin_amdgcn_s_sleep(8);
      }
    }
    // ---------------- pipelined kNN consumer ----------------
    int gw = (blk-16)*8 + wid;                 // [0,1920)
    for (int qi = gw; qi < BB*MM; qi += 1920){
      int b = qi & 15, m = qi >> 4;
      int q2 = b*MM + m;
      // wait for centroid m to be published
      {
        int pv = 0;
        for (int sp = 0; sp < (1<<20); ++sp){
          if (lane == 0) pv = __hip_atomic_load(&prog[b*16], __ATOMIC_ACQUIRE, __HIP_MEMORY_SCOPE_AGENT);
          pv = __shfl(pv, 0);
          if (pv > m) break;
          __builtin_amdgcn_s_sleep(8);
        }
      }
      const float4 qv = *(const float4*)(p2w + (size_t)q2*4);
      const float4* pbn = p1n + (size_t)b*NN;
      float bd[16]; int bi[16];
      #pragma unroll
      for (int s=0;s<16;s++){ bd[s] = 1e30f; bi[s] = 0; }
      float wv = 1e30f; int wslot = 0;

      #define KPROC(T, PV) { \
        float dot = fmaf(qv.z, (PV).z, fmaf(qv.y, (PV).y, __fmul_rn(qv.x, (PV).x))); \
        float d2 = __fsub_rn(__fadd_rn(qv.w, (PV).w), __fmul_rn(2.0f, dot)); \
        if (d2 < wv){ \
          int c = (T)*64 + lane; \
          _Pragma("unroll") \
          for (int s=0;s<16;s++) if (s==wslot){ bd[s]=d2; bi[s]=c; } \
          wv = bd[0]; wslot = 0; \
          _Pragma("unroll") \
          for (int s=1;s<16;s++) if (bd[s] > wv){ wv = bd[s]; wslot = s; } \
        } }

      float4 cur = pbn[lane];
      for (int t=0;t<63;t++){
        float4 nx = pbn[(t+1)*64 + lane];
        KPROC(t, cur);
        cur = nx;
      }
      KPROC(63, cur);
      #undef KPROC

      float lv = bd[0]; int ls = 0;
      #pragma unroll
      for (int s=1;s<16;s++) if (bd[s] < lv){ lv = bd[s]; ls = s; }
      for (int r=0;r<16;r++){
        float rv = lv; int rl = lane;
        #pragma unroll
        for (int off=32; off>=1; off>>=1){
          float ov = __shfl_xor(rv, off); int ol = __shfl_xor(rl, off);
          if (ov < rv || (ov == rv && ol < rl)){ rv = ov; rl = ol; }
        }
        if (lane == rl){
          int idx = 0;
          #pragma unroll
          for (int s=0;s<16;s++) if (s==ls) idx = bi[s];
          iknn[(size_t)q2*16 + r] = idx;
          #pragma unroll
          for (int s=0;s<16;s++) if (s==ls) bd[s] = 1e30f;
          lv = bd[0]; ls = 0;
          #pragma unroll
          for (int s=1;s<16;s++) if (bd[s] < lv){ lv = bd[s]; ls = s; }
        }
      }
    }
  }
}

// ---------- K4: GEMM1 via bf16 MFMA (fused gather) — round-5 verbatim ----------
__global__ __launch_bounds__(256) void k_gemm1(const __hip_bfloat16* __restrict__ xtb, const int* __restrict__ iknn,
                                               const float* __restrict__ p1, const float* __restrict__ p2w,
                                               const float* __restrict__ w1,
                                               __hip_bfloat16* __restrict__ h1, float* __restrict__ S1){
  __shared__ __hip_bfloat16 Ah[64*AP1];
  __shared__ __hip_bfloat16 Bh[128*AP1];
  __shared__ __hip_bfloat16 Dh[64*AP2];
  __shared__ float ssum[128], ssq[128];
  int tid = threadIdx.x;
  int r0 = blockIdx.x * 64;
  int b = r0 >> 14;
  if (tid < 128){ ssum[tid]=0.f; ssq[tid]=0.f; }
  for (int e = tid; e < 128*96; e += 256){
    int o = e / 96, k = e - o*96;
    float v = (k < 64) ? w1[o*67 + 3 + k] : ((k < 67) ? w1[o*67 + (k-64)] : 0.f);
    ((uint16_t*)Bh)[o*AP1 + k] = f2bf1(v);
  }
  if (tid < 128){
    int row = tid >> 1, hf = tid & 1;
    int n = iknn[r0 + row];
    const uint4* s4 = (const uint4*)(xtb + ((size_t)(b*NN + n))*64 + hf*32);
    uint4* d4 = (uint4*)(Ah + row*AP1 + hf*32);
    #pragma unroll
    for (int j=0;j<4;j++) d4[j] = s4[j];
  } else {
    int t2 = tid - 128;
    int row = t2 >> 1, part = t2 & 1;
    uint4* d4 = (uint4*)(Ah + row*AP1 + 64 + part*16);
    if (part == 0){
      int r = r0 + row;
      int n = iknn[r];
      int mg = r >> 4;
      const float* pp = p1 + ((size_t)(b*NN + n))*3;
      const float* qq = p2w + (size_t)mg*4;
      float rx = __fsub_rn(pp[0], qq[0]);
      float ry = __fsub_rn(pp[1], qq[1]);
      float rz = __fsub_rn(pp[2], qq[2]);
      d4[0] = make_uint4(f2bf_pk(rx, ry), f2bf_pk(rz, 0.f), 0u, 0u);
      d4[1] = make_uint4(0u,0u,0u,0u);
    } else {
      d4[0] = make_uint4(0u,0u,0u,0u);
      d4[1] = make_uint4(0u,0u,0u,0u);
    }
  }
  __syncthreads();
  int lane = tid & 63, wid = tid >> 6;
  int m0 = wid*16, ml = lane & 15, quad = lane >> 4;
  short8v af[3];
  #pragma unroll
  for (int kc=0;kc<3;kc++)
    af[kc] = *(const short8v*)(Ah + (m0+ml)*AP1 + kc*32 + quad*8);
  floatx4 acc[8];
  #pragma unroll
  for (int ct=0;ct<8;ct++) acc[ct] = (floatx4){0.f,0.f,0.f,0.f};
  #pragma unroll
  for (int ct=0;ct<8;ct++){
    #pragma unroll
    for (int kc=0;kc<3;kc++){
      short8v bf = *(const short8v*)(Bh + (ct*16+ml)*AP1 + kc*32 + quad*8);
      acc[ct] = __builtin_amdgcn_mfma_f32_16x16x32_bf16(af[kc], bf, acc[ct], 0, 0, 0);
    }
  }
  float csum[8], csq[8];
  #pragma unroll
  for (int ct=0;ct<8;ct++){
    float a0=acc[ct][0], a1=acc[ct][1], a2=acc[ct][2], a3=acc[ct][3];
    float s = (a0+a1)+(a2+a3);
    float qq2 = (a0*a0+a1*a1)+(a2*a2+a3*a3);
    s += __shfl_xor(s,16);  s += __shfl_xor(s,32);
    qq2 += __shfl_xor(qq2,16); qq2 += __shfl_xor(qq2,32);
    csum[ct]=s; csq[ct]=qq2;
    #pragma unroll
    for (int r=0;r<4;r++)
      ((uint16_t*)Dh)[(m0 + quad*4 + r)*AP2 + ct*16 + ml] = f2bf1(acc[ct][r]);
  }
  #pragma unroll
  for (int j=0;j<2;j++){
    int ct = quad*2 + j, col = ct*16 + ml;
    atomicAdd(&ssum[col], csum[ct]);
    atomicAdd(&ssq[col],  csq[ct]);
  }
  __syncthreads();
  {
    int row = tid >> 2, seg = tid & 3;
    uint4* dst = (uint4*)(h1 + ((size_t)(r0+row))*128 + seg*32);
    const uint4* s4 = (const uint4*)(Dh + row*AP2 + seg*32);
    #pragma unroll
    for (int q2=0;q2<4;q2++) dst[q2] = s4[q2];
  }
  int cp = (blockIdx.x & 31)*256;
  if (tid < 128){ atomicAdd(&S1[cp+tid], ssum[tid]); atomicAdd(&S1[cp+128+tid], ssq[tid]); }
}

// ---------- K5/K7: finalize BN scale/shift — round-5 verbatim ----------
__global__ void k_fin(const float* __restrict__ g, const float* __restrict__ bbias,
                      const float* __restrict__ S, float* __restrict__ P){
  int o = threadIdx.x;
  float s=0.f, q=0.f;
  for (int c=0;c<32;c++){ s += S[c*256+o]; q += S[c*256+128+o]; }
  float inv = 1.0f / (float)RTOT;
  float mean = s * inv;
  float var  = q * inv - mean*mean;
  float rs = 1.0f / sqrtf(var + 1e-5f);
  float scv = g[o] * rs;
  P[o]     = scv;
  P[128+o] = bbias[o] - mean*scv;
}

// ---------- K6: GEMM2 bf16 MFMA + fused k-pool extrema — round-5 verbatim ----------
__global__ __launch_bounds__(256) void k_gemm2(const __hip_bfloat16* __restrict__ h1,
                                               const float* __restrict__ w2,
                                               const float* __restrict__ P1,
                                               float* __restrict__ S2,
                                               float* __restrict__ hmax, float* __restrict__ hmin){
  __shared__ __hip_bfloat16 Ah[64*AP2];
  __shared__ __hip_bfloat16 Bh[128*AP2];
  __shared__ float scb[128], shb[128], ssum[128], ssq[128];
  int tid = threadIdx.x;
  int r0 = blockIdx.x * 64;
  if (tid < 128){ scb[tid] = P1[tid]; shb[tid] = P1[128+tid]; ssum[tid]=0.f; ssq[tid]=0.f; }
  __syncthreads();
  {
    int row = tid >> 2, seg = tid & 3;
    const uint4* hp4 = (const uint4*)(h1 + ((size_t)(r0+row))*128 + seg*32);
    #pragma unroll
    for (int q=0;q<4;q++){
      uint4 u = hp4[q];
      int cg = seg*32 + q*8;
      uint32_t wv[4] = {u.x,u.y,u.z,u.w};
      uint32_t ov[4];
      #pragma unroll
      for (int t=0;t<4;t++){
        int c = cg + t*2;
        float a0 = fmaxf(fmaf(bflo(wv[t]), scb[c],   shb[c]),   0.f);
        float a1 = fmaxf(fmaf(bfhi(wv[t]), scb[c+1], shb[c+1]), 0.f);
        ov[t] = f2bf_pk(a0, a1);
      }
      *(uint4*)(Ah + row*AP2 + cg) = make_uint4(ov[0],ov[1],ov[2],ov[3]);
    }
  }
  {
    int o = tid >> 1, hf = tid & 1;
    const float4* wr = (const float4*)(w2 + (size_t)o*128 + hf*64);
    uint32_t* bd = (uint32_t*)(Bh + o*AP2 + hf*64);
    #pragma unroll
    for (int q=0;q<16;q++){
      float4 v = wr[q];
      bd[2*q]   = f2bf_pk(v.x, v.y);
      bd[2*q+1] = f2bf_pk(v.z, v.w);
    }
  }
  __syncthreads();
  int lane = tid & 63, wid = tid >> 6;
  int m0 = wid*16, ml = lane & 15, quad = lane >> 4;
  short8v af[4];
  #pragma unroll
  for (int kc=0;kc<4;kc++)
    af[kc] = *(const short8v*)(Ah + (m0+ml)*AP2 + kc*32 + quad*8);
  floatx4 acc[8];
  #pragma unroll
  for (int ct=0;ct<8;ct++) acc[ct] = (floatx4){0.f,0.f,0.f,0.f};
  #pragma unroll
  for (int ct=0;ct<8;ct++){
    #pragma unroll
    for (int kc=0;kc<4;kc++){
      short8v bf = *(const short8v*)(Bh + (ct*16+ml)*AP2 + kc*32 + quad*8);
      acc[ct] = __builtin_amdgcn_mfma_f32_16x16x32_bf16(af[kc], bf, acc[ct], 0, 0, 0);
    }
  }
  int mrow = (r0 >> 4) + wid;
  float cm[8], cn[8], cs[8], cq[8];
  #pragma unroll
  for (int ct=0;ct<8;ct++){
    float a0=acc[ct][0], a1=acc[ct][1], a2=acc[ct][2], a3=acc[ct][3];
    float mx = fmaxf(fmaxf(a0,a1), fmaxf(a2,a3));
    float mn = fminf(fminf(a0,a1), fminf(a2,a3));
    float s  = (a0+a1)+(a2+a3);
    float q2 = (a0*a0+a1*a1)+(a2*a2+a3*a3);
    mx = fmaxf(mx, __shfl_xor(mx,16)); mx = fmaxf(mx, __shfl_xor(mx,32));
    mn = fminf(mn, __shfl_xor(mn,16)); mn = fminf(mn, __shfl_xor(mn,32));
    s += __shfl_xor(s,16);  s += __shfl_xor(s,32);
    q2 += __shfl_xor(q2,16); q2 += __shfl_xor(q2,32);
    cm[ct]=mx; cn[ct]=mn; cs[ct]=s; cq[ct]=q2;
  }
  #pragma unroll
  for (int j=0;j<2;j++){
    int ct = quad*2 + j, col = ct*16 + ml;
    hmax[(size_t)mrow*128 + col] = cm[ct];
    hmin[(size_t)mrow*128 + col] = cn[ct];
    atomicAdd(&ssum[col], cs[ct]);
    atomicAdd(&ssq[col],  cq[ct]);
  }
  __syncthreads();
  int cp = (blockIdx.x & 31)*256;
  if (tid < 128){ atomicAdd(&S2[cp+tid], ssum[tid]); atomicAdd(&S2[cp+128+tid], ssq[tid]); }
}

// ---------- K8: bn2+relu on pooled extrema — round-5 verbatim ----------
__global__ __launch_bounds__(256) void k_pool(const float* __restrict__ hmax, const float* __restrict__ hmin,
                                              const float* __restrict__ P2, float* __restrict__ out1){
  __shared__ float ot[128*65];
  __shared__ float scs[128], shs[128];
  int tid = threadIdx.x, blk = blockIdx.x;
  int b = blk >> 4, m0 = (blk & 15) * 64;
  if (tid < 128){ scs[tid]=P2[tid]; shs[tid]=P2[128+tid]; }
  __syncthreads();
  int ml = tid >> 2, oq = tid & 3, o0 = oq*32;
  int gm = b*MM + m0 + ml;
  const float4* xr = (const float4*)(hmax + (size_t)gm*128 + o0);
  const float4* nr = (const float4*)(hmin + (size_t)gm*128 + o0);
  #pragma unroll
  for (int j2=0;j2<8;j2++){
    float4 hx = xr[j2], hn = nr[j2];
    float hv[4] = {hx.x, hx.y, hx.z, hx.w};
    float nv[4] = {hn.x, hn.y, hn.z, hn.w};
    #pragma unroll
    for (int e=0;e<4;e++){
      int c = o0 + j2*4 + e;
      float sc = scs[c], sh = shs[c];
      float h = (sc >= 0.f) ? hv[e] : nv[e];
      ot[c*65 + ml] = fmaxf(fmaf(h, sc, sh), 0.f);
    }
  }
  __syncthreads();
  int o = tid >> 1, mh = tid & 1;
  float* dst = out1 + ((size_t)(b*COUT + o))*MM + m0 + mh*32;
  #pragma unroll
  for (int j2=0;j2<8;j2++){
    float4 v;
    v.x=ot[o*65+mh*32+j2*4+0]; v.y=ot[o*65+mh*32+j2*4+1];
    v.z=ot[o*65+mh*32+j2*4+2]; v.w=ot[o*65+mh*32+j2*4+3];
    *(float4*)(dst + j2*4) = v;
  }
}

extern "C" void kernel_launch(void* const* d_in, const int* in_sizes, int n_in,
                              void* d_out, int out_size, void* d_ws, size_t ws_size,
                              hipStream_t stream) {
  (void)in_sizes; (void)n_in; (void)out_size; (void)ws_size;
  const float* p1 = (const float*)d_in[0];
  const float* x1 = (const float*)d_in[1];
  const float* w1 = (const float*)d_in[2];
  const float* g1 = (const float*)d_in[3];
  const float* b1 = (const float*)d_in[4];
  const float* w2 = (const float*)d_in[5];
  const float* g2 = (const float*)d_in[6];
  const float* b2 = (const float*)d_in[7];
  float* out = (float*)d_out;
  float* ws  = (float*)d_ws;

  // ws map (float indices) — round-5 layout + sync vars at the end
  uint16_t* xtb = (uint16_t*)ws;                    // [B,N,64] bf16
  float4* p1n   = (float4*)(ws + 2097152);          // [B,N]
  int*    iknn  = (int*)(ws + 2359296);             // [B,M,16]
  float*  p2w   = ws + 2621440;                     // [B,M,4]
  float*  S1    = ws + 2686976;                     // 8192
  float*  S2    = ws + 2695168;                     // 8192
  float*  P1    = ws + 2703360;                     //  256
  float*  P2    = ws + 2703616;                     //  256
  uint16_t* h1  = (uint16_t*)(ws + 2703872);        // [R,128] bf16
  float*  hmax  = ws + 19481088;                    // [B*M,128]
  float*  hmin  = ws + 21578240;                    // [B*M,128]
  int*    prog  = (int*)(ws + 23675392);            // 16 batches x stride 16
  int*    prep_done = (int*)(ws + 23675392) + 256;
  float*  outp2 = out;                              // [B,M,3]
  float*  out1  = out + 49152;                      // [B,128,M]

  hipMemsetAsync(prog, 0, 2048, stream);            // prog + prep_done

  void* args[] = { (void*)&p1, (void*)&x1, (void*)&outp2, (void*)&p2w,
                   (void*)&p1n, (void*)&xtb, (void*)&S1,
                   (void*)&iknn, (void*)&prog, (void*)&prep_done };
  hipLaunchCooperativeKernel((void*)k_pre2, dim3(256), dim3(512), args, 0, stream);

  k_gemm1<<<4096, 256, 0, stream>>>((const __hip_bfloat16*)xtb, iknn, p1, p2w, w1,
                                    (__hip_bfloat16*)h1, S1);
  k_fin<<<1, 128, 0, stream>>>(g1, b1, S1, P1);
  k_gemm2<<<4096, 256, 0, stream>>>((const __hip_bfloat16*)h1, w2, P1, S2, hmax, hmin);
  k_fin<<<1, 128, 0, stream>>>(g2, b2, S2, P2);
  k_pool<<<256, 256, 0, stream>>>(hmax, hmin, P2, out1);
}

// Round 9
// 1268.050 us; speedup vs baseline: 1.3992x; 1.0725x over previous
//
#include <hip/hip_runtime.h>
#include <hip/hip_bf16.h>
#include <hip/hip_cooperative_groups.h>
#include <cstdint>

namespace cg = cooperative_groups;

// Problem constants
#define BB 16
#define NN 4096
#define MM 1024
#define KNB 16
#define CIN 64
#define COUT 128
#define RTOT (BB*MM*KNB)   // 262144 rows
#define AP1 104            // gemm1 LDS row stride (96 used + 8 pad), bf16
#define AP2 136            // gemm2 LDS row stride (128 + 8 pad), bf16

typedef __attribute__((ext_vector_type(8))) short short8v;
typedef __attribute__((ext_vector_type(4))) float floatx4;

// ---------- helpers ----------
__device__ __forceinline__ float bflo(uint32_t u){ return __uint_as_float(u << 16); }
__device__ __forceinline__ float bfhi(uint32_t u){ return __uint_as_float(u & 0xffff0000u); }
__device__ __forceinline__ uint32_t f2bf_pk(float a, float b){
  uint32_t ua = __float_as_uint(a), ub = __float_as_uint(b);
  ua += 0x7fffu + ((ua >> 16) & 1u);   // RNE
  ub += 0x7fffu + ((ub >> 16) & 1u);
  return (ua >> 16) | (ub & 0xffff0000u);
}
__device__ __forceinline__ uint16_t f2bf1(float a){
  uint32_t u = __float_as_uint(a);
  u += 0x7fffu + ((u >> 16) & 1u);
  return (uint16_t)(u >> 16);
}

// ---------- LDS ----------
struct FpsS { float pc[NN*3]; float4 sel[MM]; float2 cand[2][32]; };      // 66048 B
struct TrS  { float t[64][65]; };                                         // 16640 B
union PreU  { FpsS fps; TrS tr; };

// ================= K1: FPS (blocks 0-15, incremental p2w publishing) ||
//                       prework then pipelined kNN (blocks 16-255) =================
// Flush v2: lanes 64-95 write the 32-entry p2w batch in ONE wave-wide store
// instruction; release atomic by tid 64 drains the wave's stores (vmcnt is
// per-wave) before publishing prog[b]. Selection/knn arithmetic bit-identical.
__global__ __launch_bounds__(512, 2) void k_pre2(
    const float* __restrict__ p1, const float* __restrict__ x1,
    float* __restrict__ outp2, float* __restrict__ p2w,
    float4* __restrict__ p1n, uint16_t* __restrict__ xtb, float* __restrict__ Sz,
    int* __restrict__ iknn, int* __restrict__ prog, int* __restrict__ prep_done)
{
  __shared__ PreU u;
  const int blk = blockIdx.x, tid = threadIdx.x;
  const int lane = tid & 63, wid = tid >> 6;

  if (blk < 16){
    // ---------------- FPS producer ----------------
    int b = blk;
    const float* pb = p1 + (size_t)b*NN*3;
    float4 f[6];
    const float4* src = (const float4*)(pb + tid*24);
    #pragma unroll
    for (int j=0;j<6;j++) f[j] = src[j];
    #pragma unroll
    for (int j=0;j<6;j++) *(float4*)(u.fps.pc + tid*24 + j*4) = f[j];
    const float* fa = (const float*)f;
    float px[8],py[8],pz[8],dist[8];
    #pragma unroll
    for (int j=0;j<8;j++){ px[j]=fa[3*j]; py[j]=fa[3*j+1]; pz[j]=fa[3*j+2]; dist[j]=1e10f; }
    __syncthreads();
    float cx = u.fps.pc[0], cy = u.fps.pc[1], cz = u.fps.pc[2];
    if (tid==64) u.fps.sel[0] = make_float4(cx, cy, cz, 0.f);
    int g0 = tid*8;

    #define DPP_STEP(ctrl) { \
      int ov_i = __builtin_amdgcn_update_dpp(__float_as_int(mval), __float_as_int(mval), (ctrl), 0xf, 0xf, false); \
      int oi   = __builtin_amdgcn_update_dpp(midx, midx, (ctrl), 0xf, 0xf, false); \
      float ov = __int_as_float(ov_i); \
      if (ov > mval || (ov == mval && oi < midx)){ mval = ov; midx = oi; } }

    for (int i=1;i<MM;i++){
      float nd[8];
      #pragma unroll
      for (int j=0;j<8;j++){
        float dx=__fsub_rn(px[j],cx), dy=__fsub_rn(py[j],cy), dz=__fsub_rn(pz[j],cz);
        float d = __fadd_rn(__fadd_rn(__fmul_rn(dx,dx),__fmul_rn(dy,dy)),__fmul_rn(dz,dz));
        nd[j] = fminf(dist[j], d); dist[j] = nd[j];
      }
      float tv[4]; int ti[4];
      #pragma unroll
      for (int j=0;j<4;j++){
        bool r = nd[2*j+1] > nd[2*j];
        tv[j] = r ? nd[2*j+1] : nd[2*j];
        ti[j] = g0 + 2*j + (r ? 1 : 0);
      }
      { bool r = tv[1] > tv[0]; tv[0] = r?tv[1]:tv[0]; ti[0] = r?ti[1]:ti[0]; }
      { bool r = tv[3] > tv[2]; tv[2] = r?tv[3]:tv[2]; ti[2] = r?ti[3]:ti[2]; }
      bool rr = tv[2] > tv[0];
      float mval = rr ? tv[2] : tv[0];
      int   midx = rr ? ti[2] : ti[0];
      DPP_STEP(0xB1); DPP_STEP(0x4E); DPP_STEP(0x124); DPP_STEP(0x128);
      int pbuf = i & 1;
      if ((lane & 15) == 0) u.fps.cand[pbuf][wid*4 + (lane>>4)] = make_float2(mval, __int_as_float(midx));
      __syncthreads();
      float2 c0 = u.fps.cand[pbuf][lane & 15];
      float2 c1 = u.fps.cand[pbuf][16 + (lane & 15)];
      mval = c0.x; midx = __float_as_int(c0.y);
      { if (c1.x > mval){ mval = c1.x; midx = __float_as_int(c1.y); } }
      DPP_STEP(0xB1); DPP_STEP(0x4E); DPP_STEP(0x124); DPP_STEP(0x128);
      cx = u.fps.pc[midx*3+0]; cy = u.fps.pc[midx*3+1]; cz = u.fps.pc[midx*3+2];
      if (tid==64) u.fps.sel[i] = make_float4(cx, cy, cz, 0.f);
      if ((i & 31) == 31 && wid == 1 && lane < 32){
        int e = i - 31 + lane;
        float4 s = u.fps.sel[e];
        float n2 = __fadd_rn(__fadd_rn(__fmul_rn(s.x,s.x),__fmul_rn(s.y,s.y)),__fmul_rn(s.z,s.z));
        *(float4*)(p2w + ((size_t)b*MM + e)*4) = make_float4(s.x, s.y, s.z, n2);
        if (lane == 0)
          __hip_atomic_store(&prog[b*16], i+1, __ATOMIC_RELEASE, __HIP_MEMORY_SCOPE_AGENT);
      }
    }
    #undef DPP_STEP
    __syncthreads();
    // outp2 final dump (not consumed in-kernel)
    for (int e = tid; e < MM; e += 512){
      float4 s = u.fps.sel[e];
      float* o = outp2 + ((size_t)b*MM + e)*3;
      o[0]=s.x; o[1]=s.y; o[2]=s.z;
    }
  } else {
    // ---------------- prework ----------------
    for (int i = (blk-16)*512 + tid; i < 16384; i += 240*512) Sz[i] = 0.f;
    for (int i = (blk-16)*512 + tid; i < BB*NN; i += 240*512){
      float x = p1[(size_t)i*3+0], y = p1[(size_t)i*3+1], z = p1[(size_t)i*3+2];
      float n = __fadd_rn(__fadd_rn(__fmul_rn(x,x),__fmul_rn(y,y)),__fmul_rn(z,z));
      p1n[i] = make_float4(x,y,z,n);
    }
    for (int tile = blk-16; tile < 1024; tile += 240){
      int b = tile >> 6, n0 = (tile & 63)*64;
      __syncthreads();
      int c = tid >> 3, q = tid & 7;
      const float* src = x1 + ((size_t)(b*64 + c))*NN + n0 + q*8;
      float4 f0 = *(const float4*)src, f1 = *(const float4*)(src+4);
      u.tr.t[c][q*8+0]=f0.x; u.tr.t[c][q*8+1]=f0.y; u.tr.t[c][q*8+2]=f0.z; u.tr.t[c][q*8+3]=f0.w;
      u.tr.t[c][q*8+4]=f1.x; u.tr.t[c][q*8+5]=f1.y; u.tr.t[c][q*8+6]=f1.z; u.tr.t[c][q*8+7]=f1.w;
      __syncthreads();
      int n = tid >> 3;
      uint32_t* dst = (uint32_t*)(xtb + ((size_t)(b*NN + n0 + n))*64 + q*8);
      #pragma unroll
      for (int j=0;j<4;j++)
        dst[j] = f2bf_pk(u.tr.t[q*8+2*j][n], u.tr.t[q*8+2*j+1][n]);
    }
    __threadfence();
    __syncthreads();
    if (tid == 0) atomicAdd(prep_done, 1);
    {
      int pv = 0;
      for (int sp = 0; sp < (1<<20); ++sp){
        if (lane == 0) pv = __hip_atomic_load(prep_done, __ATOMIC_ACQUIRE, __HIP_MEMORY_SCOPE_AGENT);
        pv = __shfl(pv, 0);
        if (pv >= 240) break;
        __builtin_amdgcn_s_sleep(8);
      }
    }
    // ---------------- pipelined kNN consumer ----------------
    int gw = (blk-16)*8 + wid;                 // [0,1920)
    for (int qi = gw; qi < BB*MM; qi += 1920){
      int b = qi & 15, m = qi >> 4;
      int q2 = b*MM + m;
      {
        int pv = 0;
        for (int sp = 0; sp < (1<<20); ++sp){
          if (lane == 0) pv = __hip_atomic_load(&prog[b*16], __ATOMIC_ACQUIRE, __HIP_MEMORY_SCOPE_AGENT);
          pv = __shfl(pv, 0);
          if (pv > m) break;
          __builtin_amdgcn_s_sleep(8);
        }
      }
      const float4 qv = *(const float4*)(p2w + (size_t)q2*4);
      const float4* pbn = p1n + (size_t)b*NN;
      float bd[16]; int bi[16];
      #pragma unroll
      for (int s=0;s<16;s++){ bd[s] = 1e30f; bi[s] = 0; }
      float wv = 1e30f; int wslot = 0;

      #define KPROC(T, PV) { \
        float dot = fmaf(qv.z, (PV).z, fmaf(qv.y, (PV).y, __fmul_rn(qv.x, (PV).x))); \
        float d2 = __fsub_rn(__fadd_rn(qv.w, (PV).w), __fmul_rn(2.0f, dot)); \
        if (d2 < wv){ \
          int c = (T)*64 + lane; \
          _Pragma("unroll") \
          for (int s=0;s<16;s++) if (s==wslot){ bd[s]=d2; bi[s]=c; } \
          wv = bd[0]; wslot = 0; \
          _Pragma("unroll") \
          for (int s=1;s<16;s++) if (bd[s] > wv){ wv = bd[s]; wslot = s; } \
        } }

      float4 cur = pbn[lane];
      for (int t=0;t<63;t++){
        float4 nx = pbn[(t+1)*64 + lane];
        KPROC(t, cur);
        cur = nx;
      }
      KPROC(63, cur);
      #undef KPROC

      float lv = bd[0]; int ls = 0;
      #pragma unroll
      for (int s=1;s<16;s++) if (bd[s] < lv){ lv = bd[s]; ls = s; }
      for (int r=0;r<16;r++){
        float rv = lv; int rl = lane;
        #pragma unroll
        for (int off=32; off>=1; off>>=1){
          float ov = __shfl_xor(rv, off); int ol = __shfl_xor(rl, off);
          if (ov < rv || (ov == rv && ol < rl)){ rv = ov; rl = ol; }
        }
        if (lane == rl){
          int idx = 0;
          #pragma unroll
          for (int s=0;s<16;s++) if (s==ls) idx = bi[s];
          iknn[(size_t)q2*16 + r] = idx;
          #pragma unroll
          for (int s=0;s<16;s++) if (s==ls) bd[s] = 1e30f;
          lv = bd[0]; ls = 0;
          #pragma unroll
          for (int s=1;s<16;s++) if (bd[s] < lv){ lv = bd[s]; ls = s; }
        }
      }
    }
  }
}

// ---------- K4: GEMM1 bf16 MFMA (fused gather), persistent: 4 tiles/block ----------
__global__ __launch_bounds__(256) void k_gemm1(const __hip_bfloat16* __restrict__ xtb, const int* __restrict__ iknn,
                                               const float* __restrict__ p1, const float* __restrict__ p2w,
                                               const float* __restrict__ w1,
                                               __hip_bfloat16* __restrict__ h1, float* __restrict__ S1){
  __shared__ __hip_bfloat16 Ah[64*AP1];
  __shared__ __hip_bfloat16 Bh[128*AP1];
  __shared__ __hip_bfloat16 Dh[64*AP2];
  __shared__ float ssum[128], ssq[128];
  int tid = threadIdx.x;
  if (tid < 128){ ssum[tid]=0.f; ssq[tid]=0.f; }
  for (int e = tid; e < 128*96; e += 256){
    int o = e / 96, k = e - o*96;
    float v = (k < 64) ? w1[o*67 + 3 + k] : ((k < 67) ? w1[o*67 + (k-64)] : 0.f);
    ((uint16_t*)Bh)[o*AP1 + k] = f2bf1(v);
  }
  int lane = tid & 63, wid = tid >> 6;
  int m0 = wid*16, ml = lane & 15, quad = lane >> 4;
  for (int j = 0; j < 4; j++){
    int r0 = (blockIdx.x*4 + j) * 64;
    int b = r0 >> 14;
    if (j) __syncthreads();           // protect Ah/Dh from previous tile's readers
    if (tid < 128){
      int row = tid >> 1, hf = tid & 1;
      int n = iknn[r0 + row];
      const uint4* s4 = (const uint4*)(xtb + ((size_t)(b*NN + n))*64 + hf*32);
      uint4* d4 = (uint4*)(Ah + row*AP1 + hf*32);
      #pragma unroll
      for (int jj=0;jj<4;jj++) d4[jj] = s4[jj];
    } else {
      int t2 = tid - 128;
      int row = t2 >> 1, part = t2 & 1;
      uint4* d4 = (uint4*)(Ah + row*AP1 + 64 + part*16);
      if (part == 0){
        int r = r0 + row;
        int n = iknn[r];
        int mg = r >> 4;
        const float* pp = p1 + ((size_t)(b*NN + n))*3;
        const float* qq = p2w + (size_t)mg*4;
        float rx = __fsub_rn(pp[0], qq[0]);
        float ry = __fsub_rn(pp[1], qq[1]);
        float rz = __fsub_rn(pp[2], qq[2]);
        d4[0] = make_uint4(f2bf_pk(rx, ry), f2bf_pk(rz, 0.f), 0u, 0u);
        d4[1] = make_uint4(0u,0u,0u,0u);
      } else {
        d4[0] = make_uint4(0u,0u,0u,0u);
        d4[1] = make_uint4(0u,0u,0u,0u);
      }
    }
    __syncthreads();
    short8v af[3];
    #pragma unroll
    for (int kc=0;kc<3;kc++)
      af[kc] = *(const short8v*)(Ah + (m0+ml)*AP1 + kc*32 + quad*8);
    floatx4 acc[8];
    #pragma unroll
    for (int ct=0;ct<8;ct++) acc[ct] = (floatx4){0.f,0.f,0.f,0.f};
    #pragma unroll
    for (int ct=0;ct<8;ct++){
      #pragma unroll
      for (int kc=0;kc<3;kc++){
        short8v bf = *(const short8v*)(Bh + (ct*16+ml)*AP1 + kc*32 + quad*8);
        acc[ct] = __builtin_amdgcn_mfma_f32_16x16x32_bf16(af[kc], bf, acc[ct], 0, 0, 0);
      }
    }
    float csum[8], csq[8];
    #pragma unroll
    for (int ct=0;ct<8;ct++){
      float a0=acc[ct][0], a1=acc[ct][1], a2=acc[ct][2], a3=acc[ct][3];
      float s = (a0+a1)+(a2+a3);
      float qq2 = (a0*a0+a1*a1)+(a2*a2+a3*a3);
      s += __shfl_xor(s,16);  s += __shfl_xor(s,32);
      qq2 += __shfl_xor(qq2,16); qq2 += __shfl_xor(qq2,32);
      csum[ct]=s; csq[ct]=qq2;
      #pragma unroll
      for (int r=0;r<4;r++)
        ((uint16_t*)Dh)[(m0 + quad*4 + r)*AP2 + ct*16 + ml] = f2bf1(acc[ct][r]);
    }
    #pragma unroll
    for (int jj=0;jj<2;jj++){
      int ct = quad*2 + jj, col = ct*16 + ml;
      atomicAdd(&ssum[col], csum[ct]);
      atomicAdd(&ssq[col],  csq[ct]);
    }
    __syncthreads();
    {
      int row = tid >> 2, seg = tid & 3;
      uint4* dst = (uint4*)(h1 + ((size_t)(r0+row))*128 + seg*32);
      const uint4* s4 = (const uint4*)(Dh + row*AP2 + seg*32);
      #pragma unroll
      for (int q2=0;q2<4;q2++) dst[q2] = s4[q2];
    }
  }
  int cp = (blockIdx.x & 31)*256;
  if (tid < 128){ atomicAdd(&S1[cp+tid], ssum[tid]); atomicAdd(&S1[cp+128+tid], ssq[tid]); }
}

// ---------- K6: GEMM2 bf16 MFMA + fused k-pool extrema, persistent: 4 tiles/block ----------
// bn1 scale/shift computed per-block from S1 (kernel boundary guarantees S1 complete)
__global__ __launch_bounds__(256) void k_gemm2(const __hip_bfloat16* __restrict__ h1,
                                               const float* __restrict__ w2,
                                               const float* __restrict__ g1v, const float* __restrict__ b1v,
                                               const float* __restrict__ S1, float* __restrict__ S2,
                                               float* __restrict__ hmax, float* __restrict__ hmin){
  __shared__ __hip_bfloat16 Ah[64*AP2];
  __shared__ __hip_bfloat16 Bh[128*AP2];
  __shared__ float scb[128], shb[128], ssum[128], ssq[128];
  int tid = threadIdx.x;
  if (tid < 128){
    float s=0.f, q=0.f;
    for (int c=0;c<32;c++){ s += S1[c*256+tid]; q += S1[c*256+128+tid]; }
    float inv = 1.0f / (float)RTOT;
    float mean = s * inv;
    float var  = q * inv - mean*mean;
    float rs = 1.0f / sqrtf(var + 1e-5f);
    float scv = g1v[tid] * rs;
    scb[tid] = scv;
    shb[tid] = b1v[tid] - mean*scv;
    ssum[tid] = 0.f; ssq[tid] = 0.f;
  }
  {
    int o = tid >> 1, hf = tid & 1;
    const float4* wr = (const float4*)(w2 + (size_t)o*128 + hf*64);
    uint32_t* bd = (uint32_t*)(Bh + o*AP2 + hf*64);
    #pragma unroll
    for (int q=0;q<16;q++){
      float4 v = wr[q];
      bd[2*q]   = f2bf_pk(v.x, v.y);
      bd[2*q+1] = f2bf_pk(v.z, v.w);
    }
  }
  __syncthreads();
  int lane = tid & 63, wid = tid >> 6;
  int m0 = wid*16, ml = lane & 15, quad = lane >> 4;
  for (int j = 0; j < 4; j++){
    int tile = blockIdx.x*4 + j;
    int r0 = tile * 64;
    if (j) __syncthreads();           // protect Ah from previous tile's readers
    {
      int row = tid >> 2, seg = tid & 3;
      const uint4* hp4 = (const uint4*)(h1 + ((size_t)(r0+row))*128 + seg*32);
      #pragma unroll
      for (int q=0;q<4;q++){
        uint4 u = hp4[q];
        int cg = seg*32 + q*8;
        uint32_t wv[4] = {u.x,u.y,u.z,u.w};
        uint32_t ov[4];
        #pragma unroll
        for (int t=0;t<4;t++){
          int c = cg + t*2;
          float a0 = fmaxf(fmaf(bflo(wv[t]), scb[c],   shb[c]),   0.f);
          float a1 = fmaxf(fmaf(bfhi(wv[t]), scb[c+1], shb[c+1]), 0.f);
          ov[t] = f2bf_pk(a0, a1);
        }
        *(uint4*)(Ah + row*AP2 + cg) = make_uint4(ov[0],ov[1],ov[2],ov[3]);
      }
    }
    __syncthreads();
    short8v af[4];
    #pragma unroll
    for (int kc=0;kc<4;kc++)
      af[kc] = *(const short8v*)(Ah + (m0+ml)*AP2 + kc*32 + quad*8);
    floatx4 acc[8];
    #pragma unroll
    for (int ct=0;ct<8;ct++) acc[ct] = (floatx4){0.f,0.f,0.f,0.f};
    #pragma unroll
    for (int ct=0;ct<8;ct++){
      #pragma unroll
      for (int kc=0;kc<4;kc++){
        short8v bf = *(const short8v*)(Bh + (ct*16+ml)*AP2 + kc*32 + quad*8);
        acc[ct] = __builtin_amdgcn_mfma_f32_16x16x32_bf16(af[kc], bf, acc[ct], 0, 0, 0);
      }
    }
    int mrow = (r0 >> 4) + wid;
    float cm[8], cn[8], cs[8], cq[8];
    #pragma unroll
    for (int ct=0;ct<8;ct++){
      float a0=acc[ct][0], a1=acc[ct][1], a2=acc[ct][2], a3=acc[ct][3];
      float mx = fmaxf(fmaxf(a0,a1), fmaxf(a2,a3));
      float mn = fminf(fminf(a0,a1), fminf(a2,a3));
      float s  = (a0+a1)+(a2+a3);
      float q2 = (a0*a0+a1*a1)+(a2*a2+a3*a3);
      mx = fmaxf(mx, __shfl_xor(mx,16)); mx = fmaxf(mx, __shfl_xor(mx,32));
      mn = fminf(mn, __shfl_xor(mn,16)); mn = fminf(mn, __shfl_xor(mn,32));
      s += __shfl_xor(s,16);  s += __shfl_xor(s,32);
      q2 += __shfl_xor(q2,16); q2 += __shfl_xor(q2,32);
      cm[ct]=mx; cn[ct]=mn; cs[ct]=s; cq[ct]=q2;
    }
    #pragma unroll
    for (int jj=0;jj<2;jj++){
      int ct = quad*2 + jj, col = ct*16 + ml;
      hmax[(size_t)mrow*128 + col] = cm[ct];
      hmin[(size_t)mrow*128 + col] = cn[ct];
      atomicAdd(&ssum[col], cs[ct]);
      atomicAdd(&ssq[col],  cq[ct]);
    }
  }
  __syncthreads();
  int cp = (blockIdx.x & 31)*256;
  if (tid < 128){ atomicAdd(&S2[cp+tid], ssum[tid]); atomicAdd(&S2[cp+128+tid], ssq[tid]); }
}

// ---------- K8: bn2+relu on pooled extrema (P2 computed per-block from S2) ----------
__global__ __launch_bounds__(256) void k_pool(const float* __restrict__ hmax, const float* __restrict__ hmin,
                                              const float* __restrict__ g2v, const float* __restrict__ b2v,
                                              const float* __restrict__ S2, float* __restrict__ out1){
  __shared__ float ot[128*65];
  __shared__ float scs[128], shs[128];
  int tid = threadIdx.x, blk = blockIdx.x;
  int b = blk >> 4, m0 = (blk & 15) * 64;
  if (tid < 128){
    float s=0.f, q=0.f;
    for (int c=0;c<32;c++){ s += S2[c*256+tid]; q += S2[c*256+128+tid]; }
    float inv = 1.0f / (float)RTOT;
    float mean = s * inv;
    float var  = q * inv - mean*mean;
    float rs = 1.0f / sqrtf(var + 1e-5f);
    float scv = g2v[tid] * rs;
    scs[tid] = scv;
    shs[tid] = b2v[tid] - mean*scv;
  }
  __syncthreads();
  int ml = tid >> 2, oq = tid & 3, o0 = oq*32;
  int gm = b*MM + m0 + ml;
  const float4* xr = (const float4*)(hmax + (size_t)gm*128 + o0);
  const float4* nr = (const float4*)(hmin + (size_t)gm*128 + o0);
  #pragma unroll
  for (int j2=0;j2<8;j2++){
    float4 hx = xr[j2], hn = nr[j2];
    float hv[4] = {hx.x, hx.y, hx.z, hx.w};
    float nv[4] = {hn.x, hn.y, hn.z, hn.w};
    #pragma unroll
    for (int e=0;e<4;e++){
      int c = o0 + j2*4 + e;
      float sc = scs[c], sh = shs[c];
      float h = (sc >= 0.f) ? hv[e] : nv[e];
      ot[c*65 + ml] = fmaxf(fmaf(h, sc, sh), 0.f);
    }
  }
  __syncthreads();
  int o = tid >> 1, mh = tid & 1;
  float* dst = out1 + ((size_t)(b*COUT + o))*MM + m0 + mh*32;
  #pragma unroll
  for (int j2=0;j2<8;j2++){
    float4 v;
    v.x=ot[o*65+mh*32+j2*4+0]; v.y=ot[o*65+mh*32+j2*4+1];
    v.z=ot[o*65+mh*32+j2*4+2]; v.w=ot[o*65+mh*32+j2*4+3];
    *(float4*)(dst + j2*4) = v;
  }
}

extern "C" void kernel_launch(void* const* d_in, const int* in_sizes, int n_in,
                              void* d_out, int out_size, void* d_ws, size_t ws_size,
                              hipStream_t stream) {
  (void)in_sizes; (void)n_in; (void)out_size; (void)ws_size;
  const float* p1 = (const float*)d_in[0];
  const float* x1 = (const float*)d_in[1];
  const float* w1 = (const float*)d_in[2];
  const float* g1 = (const float*)d_in[3];
  const float* b1 = (const float*)d_in[4];
  const float* w2 = (const float*)d_in[5];
  const float* g2 = (const float*)d_in[6];
  const float* b2 = (const float*)d_in[7];
  float* out = (float*)d_out;
  float* ws  = (float*)d_ws;

  // ws map (float indices)
  uint16_t* xtb = (uint16_t*)ws;                    // [B,N,64] bf16
  float4* p1n   = (float4*)(ws + 2097152);          // [B,N]
  int*    iknn  = (int*)(ws + 2359296);             // [B,M,16]
  float*  p2w   = ws + 2621440;                     // [B,M,4]
  float*  S1    = ws + 2686976;                     // 8192
  float*  S2    = ws + 2695168;                     // 8192
  uint16_t* h1  = (uint16_t*)(ws + 2703872);        // [R,128] bf16
  float*  hmax  = ws + 19481088;                    // [B*M,128]
  float*  hmin  = ws + 21578240;                    // [B*M,128]
  int*    prog  = (int*)(ws + 23675392);            // 16 batches x stride 16
  int*    prep_done = (int*)(ws + 23675392) + 256;
  float*  outp2 = out;                              // [B,M,3]
  float*  out1  = out + 49152;                      // [B,128,M]

  hipMemsetAsync(prog, 0, 2048, stream);            // prog + prep_done

  void* args[] = { (void*)&p1, (void*)&x1, (void*)&outp2, (void*)&p2w,
                   (void*)&p1n, (void*)&xtb, (void*)&S1,
                   (void*)&iknn, (void*)&prog, (void*)&prep_done };
  hipLaunchCooperativeKernel((void*)k_pre2, dim3(256), dim3(512), args, 0, stream);

  k_gemm1<<<1024, 256, 0, stream>>>((const __hip_bfloat16*)xtb, iknn, p1, p2w, w1,
                                    (__hip_bfloat16*)h1, S1);
  k_gemm2<<<1024, 256, 0, stream>>>((const __hip_bfloat16*)h1, w2, g1, b1, S1, S2, hmax, hmin);
  k_pool<<<256, 256, 0, stream>>>(hmax, hmin, g2, b2, S2, out1);
}

// Round 10
// 1172.713 us; speedup vs baseline: 1.5129x; 1.0813x over previous
//
#include <hip/hip_runtime.h>
#include <hip/hip_bf16.h>
#include <hip/hip_cooperative_groups.h>
#include <cstdint>

namespace cg = cooperative_groups;

// Problem constants
#define BB 16
#define NN 4096
#define MM 1024
#define KNB 16
#define CIN 64
#define COUT 128
#define RTOT (BB*MM*KNB)   // 262144 rows
#define AP1 104            // gemm1 LDS row stride (96 used + 8 pad), bf16
#define AP2 136            // gemm2 LDS row stride (128 + 8 pad), bf16

typedef __attribute__((ext_vector_type(8))) short short8v;
typedef __attribute__((ext_vector_type(4))) float floatx4;

// ---------- helpers ----------
__device__ __forceinline__ float bflo(uint32_t u){ return __uint_as_float(u << 16); }
__device__ __forceinline__ float bfhi(uint32_t u){ return __uint_as_float(u & 0xffff0000u); }
__device__ __forceinline__ uint32_t f2bf_pk(float a, float b){
  uint32_t ua = __float_as_uint(a), ub = __float_as_uint(b);
  ua += 0x7fffu + ((ua >> 16) & 1u);   // RNE
  ub += 0x7fffu + ((ub >> 16) & 1u);
  return (ua >> 16) | (ub & 0xffff0000u);
}
__device__ __forceinline__ uint16_t f2bf1(float a){
  uint32_t u = __float_as_uint(a);
  u += 0x7fffu + ((u >> 16) & 1u);
  return (uint16_t)(u >> 16);
}

// ---------- LDS ----------
struct FpsS { float pc[NN*3]; float4 sel[MM]; float2 cand[2][32]; };      // 66048 B
struct TrS  { float t[64][65]; };                                         // 16640 B
struct ConsS{ uint16_t Bh1[128*AP1]; uint16_t AhD[128*AP2];
              int winq[8*16]; float ssum[128]; float ssq[128]; };         // 62976 B
union PreU  { FpsS fps; TrS tr; ConsS cons; };

// ================= K1: FPS producer (blocks 0-15) || prework + pipelined kNN+GEMM1
//                       consumers (blocks 16-255) =================
// Consumers: poll prog[b] (acquire, s_sleep(64)) -> kNN for query m -> winners to LDS
// -> gather own 16-row A-tile -> 24 MFMAs vs block-staged w1 -> h1 rows + stats.
// Zero barriers in the consumer loop: each wave owns its 16 LDS rows; per-wave DS
// ordering guarantees stage->read->overwrite correctness. Arithmetic identical to
// the former k_gemm1. Producer: flush 64 p2w entries per publish (16 drains total).
__global__ __launch_bounds__(512, 2) void k_pre2(
    const float* __restrict__ p1, const float* __restrict__ x1,
    const float* __restrict__ w1,
    float* __restrict__ outp2, float* __restrict__ p2w,
    float4* __restrict__ p1n, uint16_t* __restrict__ xtb, float* __restrict__ Sz,
    uint16_t* __restrict__ h1, float* __restrict__ S1,
    int* __restrict__ prog, int* __restrict__ prep_done)
{
  __shared__ PreU u;
  const int blk = blockIdx.x, tid = threadIdx.x;
  const int lane = tid & 63, wid = tid >> 6;

  if (blk < 16){
    // ---------------- FPS producer ----------------
    int b = blk;
    const float* pb = p1 + (size_t)b*NN*3;
    float4 f[6];
    const float4* src = (const float4*)(pb + tid*24);
    #pragma unroll
    for (int j=0;j<6;j++) f[j] = src[j];
    #pragma unroll
    for (int j=0;j<6;j++) *(float4*)(u.fps.pc + tid*24 + j*4) = f[j];
    const float* fa = (const float*)f;
    float px[8],py[8],pz[8],dist[8];
    #pragma unroll
    for (int j=0;j<8;j++){ px[j]=fa[3*j]; py[j]=fa[3*j+1]; pz[j]=fa[3*j+2]; dist[j]=1e10f; }
    __syncthreads();
    float cx = u.fps.pc[0], cy = u.fps.pc[1], cz = u.fps.pc[2];
    if (tid==64) u.fps.sel[0] = make_float4(cx, cy, cz, 0.f);
    int g0 = tid*8;

    #define DPP_STEP(ctrl) { \
      int ov_i = __builtin_amdgcn_update_dpp(__float_as_int(mval), __float_as_int(mval), (ctrl), 0xf, 0xf, false); \
      int oi   = __builtin_amdgcn_update_dpp(midx, midx, (ctrl), 0xf, 0xf, false); \
      float ov = __int_as_float(ov_i); \
      if (ov > mval || (ov == mval && oi < midx)){ mval = ov; midx = oi; } }

    for (int i=1;i<MM;i++){
      float nd[8];
      #pragma unroll
      for (int j=0;j<8;j++){
        float dx=__fsub_rn(px[j],cx), dy=__fsub_rn(py[j],cy), dz=__fsub_rn(pz[j],cz);
        float d = __fadd_rn(__fadd_rn(__fmul_rn(dx,dx),__fmul_rn(dy,dy)),__fmul_rn(dz,dz));
        nd[j] = fminf(dist[j], d); dist[j] = nd[j];
      }
      float tv[4]; int ti[4];
      #pragma unroll
      for (int j=0;j<4;j++){
        bool r = nd[2*j+1] > nd[2*j];
        tv[j] = r ? nd[2*j+1] : nd[2*j];
        ti[j] = g0 + 2*j + (r ? 1 : 0);
      }
      { bool r = tv[1] > tv[0]; tv[0] = r?tv[1]:tv[0]; ti[0] = r?ti[1]:ti[0]; }
      { bool r = tv[3] > tv[2]; tv[2] = r?tv[3]:tv[2]; ti[2] = r?ti[3]:ti[2]; }
      bool rr = tv[2] > tv[0];
      float mval = rr ? tv[2] : tv[0];
      int   midx = rr ? ti[2] : ti[0];
      DPP_STEP(0xB1); DPP_STEP(0x4E); DPP_STEP(0x124); DPP_STEP(0x128);
      int pbuf = i & 1;
      if ((lane & 15) == 0) u.fps.cand[pbuf][wid*4 + (lane>>4)] = make_float2(mval, __int_as_float(midx));
      __syncthreads();
      float2 c0 = u.fps.cand[pbuf][lane & 15];
      float2 c1 = u.fps.cand[pbuf][16 + (lane & 15)];
      mval = c0.x; midx = __float_as_int(c0.y);
      { if (c1.x > mval){ mval = c1.x; midx = __float_as_int(c1.y); } }
      DPP_STEP(0xB1); DPP_STEP(0x4E); DPP_STEP(0x124); DPP_STEP(0x128);
      cx = u.fps.pc[midx*3+0]; cy = u.fps.pc[midx*3+1]; cz = u.fps.pc[midx*3+2];
      if (tid==64) u.fps.sel[i] = make_float4(cx, cy, cz, 0.f);
      if ((i & 63) == 63 && wid == 1){
        int e = i - 63 + lane;
        float4 s = u.fps.sel[e];
        float n2 = __fadd_rn(__fadd_rn(__fmul_rn(s.x,s.x),__fmul_rn(s.y,s.y)),__fmul_rn(s.z,s.z));
        *(float4*)(p2w + ((size_t)b*MM + e)*4) = make_float4(s.x, s.y, s.z, n2);
        if (lane == 0)
          __hip_atomic_store(&prog[b*16], i+1, __ATOMIC_RELEASE, __HIP_MEMORY_SCOPE_AGENT);
      }
    }
    #undef DPP_STEP
    __syncthreads();
    for (int e = tid; e < MM; e += 512){
      float4 s = u.fps.sel[e];
      float* o = outp2 + ((size_t)b*MM + e)*3;
      o[0]=s.x; o[1]=s.y; o[2]=s.z;
    }
  } else {
    // ---------------- prework ----------------
    for (int i = (blk-16)*512 + tid; i < 16384; i += 240*512) Sz[i] = 0.f;
    for (int i = (blk-16)*512 + tid; i < BB*NN; i += 240*512){
      float x = p1[(size_t)i*3+0], y = p1[(size_t)i*3+1], z = p1[(size_t)i*3+2];
      float n = __fadd_rn(__fadd_rn(__fmul_rn(x,x),__fmul_rn(y,y)),__fmul_rn(z,z));
      p1n[i] = make_float4(x,y,z,n);
    }
    for (int tile = blk-16; tile < 1024; tile += 240){
      int b = tile >> 6, n0 = (tile & 63)*64;
      __syncthreads();
      int c = tid >> 3, q = tid & 7;
      const float* src = x1 + ((size_t)(b*64 + c))*NN + n0 + q*8;
      float4 f0 = *(const float4*)src, f1 = *(const float4*)(src+4);
      u.tr.t[c][q*8+0]=f0.x; u.tr.t[c][q*8+1]=f0.y; u.tr.t[c][q*8+2]=f0.z; u.tr.t[c][q*8+3]=f0.w;
      u.tr.t[c][q*8+4]=f1.x; u.tr.t[c][q*8+5]=f1.y; u.tr.t[c][q*8+6]=f1.z; u.tr.t[c][q*8+7]=f1.w;
      __syncthreads();
      int n = tid >> 3;
      uint32_t* dst = (uint32_t*)(xtb + ((size_t)(b*NN + n0 + n))*64 + q*8);
      #pragma unroll
      for (int j=0;j<4;j++)
        dst[j] = f2bf_pk(u.tr.t[q*8+2*j][n], u.tr.t[q*8+2*j+1][n]);
    }
    __threadfence();
    __syncthreads();
    if (tid == 0) atomicAdd(prep_done, 1);
    // stage w1 -> Bh1 (K-perm [x(64)|rel(3)|0]); zero block stats (TrS dead; union switch)
    for (int e = tid; e < 128*96; e += 512){
      int o = e / 96, k = e - o*96;
      float v = (k < 64) ? w1[o*67 + 3 + k] : ((k < 67) ? w1[o*67 + (k-64)] : 0.f);
      u.cons.Bh1[o*AP1 + k] = f2bf1(v);
    }
    if (tid < 128){ u.cons.ssum[tid]=0.f; u.cons.ssq[tid]=0.f; }
    __syncthreads();
    // wait for all 240 prework blocks (p1n/xtb from other blocks)
    {
      int pv = 0, sp = 0;
      if (lane == 0) pv = __hip_atomic_load(prep_done, __ATOMIC_ACQUIRE, __HIP_MEMORY_SCOPE_AGENT);
      pv = __shfl(pv, 0);
      while (pv < 240 && sp < (1<<16)){
        __builtin_amdgcn_s_sleep(64);
        if (lane == 0) pv = __hip_atomic_load(prep_done, __ATOMIC_ACQUIRE, __HIP_MEMORY_SCOPE_AGENT);
        pv = __shfl(pv, 0); sp++;
      }
    }
    // ---------------- pipelined kNN + fused GEMM1, one query per wave-step ----------------
    int ml = lane & 15, quad = lane >> 4, seg = lane >> 4;
    int gw = (blk-16)*8 + wid;                 // [0,1920)
    for (int qi = gw; qi < BB*MM; qi += 1920){
      int b = qi & 15, m = qi >> 4;
      int q2 = b*MM + m;
      // wait for centroid m (acquire; 1.7us-granularity sleep to cut line contention)
      {
        int pv = 0, sp = 0;
        if (lane == 0) pv = __hip_atomic_load(&prog[b*16], __ATOMIC_ACQUIRE, __HIP_MEMORY_SCOPE_AGENT);
        pv = __shfl(pv, 0);
        while (pv <= m && sp < (1<<16)){
          __builtin_amdgcn_s_sleep(64);
          if (lane == 0) pv = __hip_atomic_load(&prog[b*16], __ATOMIC_ACQUIRE, __HIP_MEMORY_SCOPE_AGENT);
          pv = __shfl(pv, 0); sp++;
        }
      }
      const float4 qv = *(const float4*)(p2w + (size_t)q2*4);
      const float4* pbn = p1n + (size_t)b*NN;
      float bd[16]; int bi[16];
      #pragma unroll
      for (int s=0;s<16;s++){ bd[s] = 1e30f; bi[s] = 0; }
      float wv = 1e30f; int wslot = 0;

      #define KPROC(T, PV) { \
        float dot = fmaf(qv.z, (PV).z, fmaf(qv.y, (PV).y, __fmul_rn(qv.x, (PV).x))); \
        float d2 = __fsub_rn(__fadd_rn(qv.w, (PV).w), __fmul_rn(2.0f, dot)); \
        if (d2 < wv){ \
          int c = (T)*64 + lane; \
          _Pragma("unroll") \
          for (int s=0;s<16;s++) if (s==wslot){ bd[s]=d2; bi[s]=c; } \
          wv = bd[0]; wslot = 0; \
          _Pragma("unroll") \
          for (int s=1;s<16;s++) if (bd[s] > wv){ wv = bd[s]; wslot = s; } \
        } }

      float4 cur = pbn[lane];
      for (int t=0;t<63;t++){
        float4 nx = pbn[(t+1)*64 + lane];
        KPROC(t, cur);
        cur = nx;
      }
      KPROC(63, cur);
      #undef KPROC

      float lv = bd[0]; int ls = 0;
      #pragma unroll
      for (int s=1;s<16;s++) if (bd[s] < lv){ lv = bd[s]; ls = s; }
      for (int r=0;r<16;r++){
        float rv = lv; int rl = lane;
        #pragma unroll
        for (int off=32; off>=1; off>>=1){
          float ov = __shfl_xor(rv, off); int ol = __shfl_xor(rl, off);
          if (ov < rv || (ov == rv && ol < rl)){ rv = ov; rl = ol; }
        }
        if (lane == rl){
          int idx = 0;
          #pragma unroll
          for (int s=0;s<16;s++) if (s==ls) idx = bi[s];
          u.cons.winq[wid*16 + r] = idx;
          #pragma unroll
          for (int s=0;s<16;s++) if (s==ls) bd[s] = 1e30f;
          lv = bd[0]; ls = 0;
          #pragma unroll
          for (int s=1;s<16;s++) if (bd[s] < lv){ lv = bd[s]; ls = s; }
        }
      }
      // ---- fused GEMM1 for this query's 16 rows (wave-private LDS rows) ----
      int n = u.cons.winq[wid*16 + ml];        // same-wave DS order: winq writes done
      {
        const uint4* s4 = (const uint4*)(xtb + ((size_t)(b*NN + n))*64 + seg*16);
        uint4* d4 = (uint4*)(u.cons.AhD + (wid*16 + ml)*AP2 + seg*16);
        d4[0] = s4[0]; d4[1] = s4[1];
        if (seg == 0){
          const float* pp = p1 + ((size_t)(b*NN + n))*3;
          float rx = __fsub_rn(pp[0], qv.x);
          float ry = __fsub_rn(pp[1], qv.y);
          float rz = __fsub_rn(pp[2], qv.z);
          uint4* dr = (uint4*)(u.cons.AhD + (wid*16 + ml)*AP2 + 64);
          dr[0] = make_uint4(f2bf_pk(rx, ry), f2bf_pk(rz, 0.f), 0u, 0u);
          dr[1] = make_uint4(0u,0u,0u,0u);
          dr[2] = make_uint4(0u,0u,0u,0u);
          dr[3] = make_uint4(0u,0u,0u,0u);
        }
      }
      short8v af[3];
      #pragma unroll
      for (int kc=0;kc<3;kc++)
        af[kc] = *(const short8v*)(u.cons.AhD + (wid*16 + ml)*AP2 + kc*32 + quad*8);
      floatx4 acc[8];
      #pragma unroll
      for (int ct=0;ct<8;ct++) acc[ct] = (floatx4){0.f,0.f,0.f,0.f};
      #pragma unroll
      for (int ct=0;ct<8;ct++){
        #pragma unroll
        for (int kc=0;kc<3;kc++){
          short8v bf = *(const short8v*)(u.cons.Bh1 + (ct*16+ml)*AP1 + kc*32 + quad*8);
          acc[ct] = __builtin_amdgcn_mfma_f32_16x16x32_bf16(af[kc], bf, acc[ct], 0, 0, 0);
        }
      }
      float csum[8], csq[8];
      #pragma unroll
      for (int ct=0;ct<8;ct++){
        float a0=acc[ct][0], a1=acc[ct][1], a2=acc[ct][2], a3=acc[ct][3];
        float s = (a0+a1)+(a2+a3);
        float qq2 = (a0*a0+a1*a1)+(a2*a2+a3*a3);
        s += __shfl_xor(s,16);  s += __shfl_xor(s,32);
        qq2 += __shfl_xor(qq2,16); qq2 += __shfl_xor(qq2,32);
        csum[ct]=s; csq[ct]=qq2;
        #pragma unroll
        for (int r=0;r<4;r++)
          u.cons.AhD[(wid*16 + quad*4 + r)*AP2 + ct*16 + ml] = f2bf1(acc[ct][r]);
      }
      #pragma unroll
      for (int jj=0;jj<2;jj++){
        int ct = quad*2 + jj, col = ct*16 + ml;
        atomicAdd(&u.cons.ssum[col], csum[ct]);
        atomicAdd(&u.cons.ssq[col],  csq[ct]);
      }
      // coalesced h1 write of own 16 rows (reads after same-wave D writes)
      {
        const uint4* s4 = (const uint4*)(u.cons.AhD + (wid*16 + ml)*AP2 + seg*32);
        uint4* dst = (uint4*)(h1 + ((size_t)q2*16 + ml)*128 + seg*32);
        dst[0]=s4[0]; dst[1]=s4[1]; dst[2]=s4[2]; dst[3]=s4[3];
      }
    }
    __syncthreads();
    int cp = (blk & 31)*256;
    if (tid < 128){ atomicAdd(&S1[cp+tid], u.cons.ssum[tid]); atomicAdd(&S1[cp+128+tid], u.cons.ssq[tid]); }
  }
}

// ---------- K6: GEMM2 bf16 MFMA + fused k-pool extrema, persistent: 4 tiles/block ----------
__global__ __launch_bounds__(256) void k_gemm2(const __hip_bfloat16* __restrict__ h1,
                                               const float* __restrict__ w2,
                                               const float* __restrict__ g1v, const float* __restrict__ b1v,
                                               const float* __restrict__ S1, float* __restrict__ S2,
                                               float* __restrict__ hmax, float* __restrict__ hmin){
  __shared__ __hip_bfloat16 Ah[64*AP2];
  __shared__ __hip_bfloat16 Bh[128*AP2];
  __shared__ float scb[128], shb[128], ssum[128], ssq[128];
  int tid = threadIdx.x;
  if (tid < 128){
    float s=0.f, q=0.f;
    for (int c=0;c<32;c++){ s += S1[c*256+tid]; q += S1[c*256+128+tid]; }
    float inv = 1.0f / (float)RTOT;
    float mean = s * inv;
    float var  = q * inv - mean*mean;
    float rs = 1.0f / sqrtf(var + 1e-5f);
    float scv = g1v[tid] * rs;
    scb[tid] = scv;
    shb[tid] = b1v[tid] - mean*scv;
    ssum[tid] = 0.f; ssq[tid] = 0.f;
  }
  {
    int o = tid >> 1, hf = tid & 1;
    const float4* wr = (const float4*)(w2 + (size_t)o*128 + hf*64);
    uint32_t* bd = (uint32_t*)(Bh + o*AP2 + hf*64);
    #pragma unroll
    for (int q=0;q<16;q++){
      float4 v = wr[q];
      bd[2*q]   = f2bf_pk(v.x, v.y);
      bd[2*q+1] = f2bf_pk(v.z, v.w);
    }
  }
  __syncthreads();
  int lane = tid & 63, wid = tid >> 6;
  int m0 = wid*16, ml = lane & 15, quad = lane >> 4;
  for (int j = 0; j < 4; j++){
    int tile = blockIdx.x*4 + j;
    int r0 = tile * 64;
    if (j) __syncthreads();
    {
      int row = tid >> 2, seg = tid & 3;
      const uint4* hp4 = (const uint4*)(h1 + ((size_t)(r0+row))*128 + seg*32);
      #pragma unroll
      for (int q=0;q<4;q++){
        uint4 u = hp4[q];
        int cg = seg*32 + q*8;
        uint32_t wv[4] = {u.x,u.y,u.z,u.w};
        uint32_t ov[4];
        #pragma unroll
        for (int t=0;t<4;t++){
          int c = cg + t*2;
          float a0 = fmaxf(fmaf(bflo(wv[t]), scb[c],   shb[c]),   0.f);
          float a1 = fmaxf(fmaf(bfhi(wv[t]), scb[c+1], shb[c+1]), 0.f);
          ov[t] = f2bf_pk(a0, a1);
        }
        *(uint4*)(Ah + row*AP2 + cg) = make_uint4(ov[0],ov[1],ov[2],ov[3]);
      }
    }
    __syncthreads();
    short8v af[4];
    #pragma unroll
    for (int kc=0;kc<4;kc++)
      af[kc] = *(const short8v*)(Ah + (m0+ml)*AP2 + kc*32 + quad*8);
    floatx4 acc[8];
    #pragma unroll
    for (int ct=0;ct<8;ct++) acc[ct] = (floatx4){0.f,0.f,0.f,0.f};
    #pragma unroll
    for (int ct=0;ct<8;ct++){
      #pragma unroll
      for (int kc=0;kc<4;kc++){
        short8v bf = *(const short8v*)(Bh + (ct*16+ml)*AP2 + kc*32 + quad*8);
        acc[ct] = __builtin_amdgcn_mfma_f32_16x16x32_bf16(af[kc], bf, acc[ct], 0, 0, 0);
      }
    }
    int mrow = (r0 >> 4) + wid;
    float cm[8], cn[8], cs[8], cq[8];
    #pragma unroll
    for (int ct=0;ct<8;ct++){
      float a0=acc[ct][0], a1=acc[ct][1], a2=acc[ct][2], a3=acc[ct][3];
      float mx = fmaxf(fmaxf(a0,a1), fmaxf(a2,a3));
      float mn = fminf(fminf(a0,a1), fminf(a2,a3));
      float s  = (a0+a1)+(a2+a3);
      float q2 = (a0*a0+a1*a1)+(a2*a2+a3*a3);
      mx = fmaxf(mx, __shfl_xor(mx,16)); mx = fmaxf(mx, __shfl_xor(mx,32));
      mn = fminf(mn, __shfl_xor(mn,16)); mn = fminf(mn, __shfl_xor(mn,32));
      s += __shfl_xor(s,16);  s += __shfl_xor(s,32);
      q2 += __shfl_xor(q2,16); q2 += __shfl_xor(q2,32);
      cm[ct]=mx; cn[ct]=mn; cs[ct]=s; cq[ct]=q2;
    }
    #pragma unroll
    for (int jj=0;jj<2;jj++){
      int ct = quad*2 + jj, col = ct*16 + ml;
      hmax[(size_t)mrow*128 + col] = cm[ct];
      hmin[(size_t)mrow*128 + col] = cn[ct];
      atomicAdd(&ssum[col], cs[ct]);
      atomicAdd(&ssq[col],  cq[ct]);
    }
  }
  __syncthreads();
  int cp = (blockIdx.x & 31)*256;
  if (tid < 128){ atomicAdd(&S2[cp+tid], ssum[tid]); atomicAdd(&S2[cp+128+tid], ssq[tid]); }
}

// ---------- K8: bn2+relu on pooled extrema (P2 computed per-block from S2) ----------
__global__ __launch_bounds__(256) void k_pool(const float* __restrict__ hmax, const float* __restrict__ hmin,
                                              const float* __restrict__ g2v, const float* __restrict__ b2v,
                                              const float* __restrict__ S2, float* __restrict__ out1){
  __shared__ float ot[128*65];
  __shared__ float scs[128], shs[128];
  int tid = threadIdx.x, blk = blockIdx.x;
  int b = blk >> 4, m0 = (blk & 15) * 64;
  if (tid < 128){
    float s=0.f, q=0.f;
    for (int c=0;c<32;c++){ s += S2[c*256+tid]; q += S2[c*256+128+tid]; }
    float inv = 1.0f / (float)RTOT;
    float mean = s * inv;
    float var  = q * inv - mean*mean;
    float rs = 1.0f / sqrtf(var + 1e-5f);
    float scv = g2v[tid] * rs;
    scs[tid] = scv;
    shs[tid] = b2v[tid] - mean*scv;
  }
  __syncthreads();
  int ml = tid >> 2, oq = tid & 3, o0 = oq*32;
  int gm = b*MM + m0 + ml;
  const float4* xr = (const float4*)(hmax + (size_t)gm*128 + o0);
  const float4* nr = (const float4*)(hmin + (size_t)gm*128 + o0);
  #pragma unroll
  for (int j2=0;j2<8;j2++){
    float4 hx = xr[j2], hn = nr[j2];
    float hv[4] = {hx.x, hx.y, hx.z, hx.w};
    float nv[4] = {hn.x, hn.y, hn.z, hn.w};
    #pragma unroll
    for (int e=0;e<4;e++){
      int c = o0 + j2*4 + e;
      float sc = scs[c], sh = shs[c];
      float h = (sc >= 0.f) ? hv[e] : nv[e];
      ot[c*65 + ml] = fmaxf(fmaf(h, sc, sh), 0.f);
    }
  }
  __syncthreads();
  int o = tid >> 1, mh = tid & 1;
  float* dst = out1 + ((size_t)(b*COUT + o))*MM + m0 + mh*32;
  #pragma unroll
  for (int j2=0;j2<8;j2++){
    float4 v;
    v.x=ot[o*65+mh*32+j2*4+0]; v.y=ot[o*65+mh*32+j2*4+1];
    v.z=ot[o*65+mh*32+j2*4+2]; v.w=ot[o*65+mh*32+j2*4+3];
    *(float4*)(dst + j2*4) = v;
  }
}

extern "C" void kernel_launch(void* const* d_in, const int* in_sizes, int n_in,
                              void* d_out, int out_size, void* d_ws, size_t ws_size,
                              hipStream_t stream) {
  (void)in_sizes; (void)n_in; (void)out_size; (void)ws_size;
  const float* p1 = (const float*)d_in[0];
  const float* x1 = (const float*)d_in[1];
  const float* w1 = (const float*)d_in[2];
  const float* g1 = (const float*)d_in[3];
  const float* b1 = (const float*)d_in[4];
  const float* w2 = (const float*)d_in[5];
  const float* g2 = (const float*)d_in[6];
  const float* b2 = (const float*)d_in[7];
  float* out = (float*)d_out;
  float* ws  = (float*)d_ws;

  // ws map (float indices)
  uint16_t* xtb = (uint16_t*)ws;                    // [B,N,64] bf16
  float4* p1n   = (float4*)(ws + 2097152);          // [B,N]
  float*  p2w   = ws + 2621440;                     // [B,M,4]
  float*  S1    = ws + 2686976;                     // 8192
  float*  S2    = ws + 2695168;                     // 8192
  uint16_t* h1  = (uint16_t*)(ws + 2703872);        // [R,128] bf16
  float*  hmax  = ws + 19481088;                    // [B*M,128]
  float*  hmin  = ws + 21578240;                    // [B*M,128]
  int*    prog  = (int*)(ws + 23675392);            // 16 batches x stride 16
  int*    prep_done = (int*)(ws + 23675392) + 256;
  float*  outp2 = out;                              // [B,M,3]
  float*  out1  = out + 49152;                      // [B,128,M]

  hipMemsetAsync(prog, 0, 2048, stream);            // prog + prep_done

  void* args[] = { (void*)&p1, (void*)&x1, (void*)&w1,
                   (void*)&outp2, (void*)&p2w,
                   (void*)&p1n, (void*)&xtb, (void*)&S1,
                   (void*)&h1, (void*)&S1, (void*)&prog, (void*)&prep_done };
  hipLaunchCooperativeKernel((void*)k_pre2, dim3(256), dim3(512), args, 0, stream);

  k_gemm2<<<1024, 256, 0, stream>>>((const __hip_bfloat16*)h1, w2, g1, b1, S1, S2, hmax, hmin);
  k_pool<<<256, 256, 0, stream>>>(hmax, hmin, g2, b2, S2, out1);
}